// Round 31
// baseline (493.813 us; speedup 1.0000x reference)
//
#include <hip/hip_runtime.h>
#include <hip/hip_fp16.h>

#define NN    20000
#define NE    150000
#define HD    256
#define NT    4
#define NR    8
#define NH    8
#define DKq   32
#define NL    2
#define MAXL  240
#define HBLK  256
#define SCB   ((NN + 255)/256)
#define TMAX  632
#define FOLDN 79
#define FOLDC 15
#define INV_SQRT_DK 0.17677669529663687f

typedef _Float16 f16x4 __attribute__((ext_vector_type(4)));
typedef _Float16 f16x8 __attribute__((ext_vector_type(8)));
typedef float    f32x4v __attribute__((ext_vector_type(4)));

// ---------- node bucketing (by type) + compact 32-row tile list ----------
__global__ __launch_bounds__(256) void k_nhist(const int* __restrict__ ntype, int* __restrict__ nhist)
{
    __shared__ int h[NT];
    const int tid = threadIdx.x, b = blockIdx.x;
    if (tid < NT) h[tid] = 0;
    __syncthreads();
    const int cn = (NN + HBLK-1)/HBLK;
    const int nEnd = min((b+1)*cn, NN);
    for (int i = b*cn + tid; i < nEnd; i += 256) atomicAdd(&h[ntype[i]], 1);
    __syncthreads();
    if (tid < NT) nhist[b*NT + tid] = h[tid];
}
__global__ void k_nscan(const int* __restrict__ nhist, int* __restrict__ noff, int* __restrict__ nbase,
                        int* __restrict__ tlist, int* __restrict__ tcount)
{
    __shared__ int tot[NT];
    const int tid = threadIdx.x;
    if (tid < NT){
        int s = 0;
        for (int b = 0; b < HBLK; b++) s += nhist[b*NT + tid];
        tot[tid] = s;
    }
    __syncthreads();
    if (tid == 0){ noff[0]=0; for (int t=0;t<NT;t++) noff[t+1]=noff[t]+tot[t]; }
    if (tid < NT){
        int base = 0; for (int t=0;t<tid;t++) base += tot[t];
        int run = 0;
        for (int b=0;b<HBLK;b++){ nbase[b*NT+tid] = base + run; run += nhist[b*NT+tid]; }
    }
    __syncthreads();
    if (tid == 0){
        int c = 0;
        for (int t = 0; t < NT; t++){
            const int ntile = (tot[t] + 31) >> 5;
            for (int rt = 0; rt < ntile; rt++) tlist[c++] = (t << 20) | rt;
        }
        *tcount = c;
    }
}
__global__ __launch_bounds__(256) void k_nscatter(const int* __restrict__ ntype,
    const int* __restrict__ nbase, int* __restrict__ nbucket)
{
    __shared__ int cur[NT];
    const int tid = threadIdx.x, b = blockIdx.x;
    if (tid < NT) cur[tid] = nbase[b*NT + tid];
    __syncthreads();
    const int cn = (NN + HBLK-1)/HBLK;
    const int nEnd = min((b+1)*cn, NN);
    for (int i = b*cn + tid; i < nEnd; i += 256)
        nbucket[atomicAdd(&cur[ntype[i]], 1)] = i;
}

// ---------- edge CSR build: sort by tgt ----------
__global__ void k_zero_bins(int* __restrict__ cnt){
    int i = blockIdx.x*256 + threadIdx.x;
    if (i < NN) cnt[i] = 0;
}
__global__ void k_csr_hist(const int* __restrict__ ei, int* __restrict__ cnt){
    int e = blockIdx.x*256 + threadIdx.x;
    if (e >= NE) return;
    atomicAdd(&cnt[ei[NE+e]], 1);
}
__global__ __launch_bounds__(256) void k_scan1(const int* __restrict__ cnt,
    int* __restrict__ tgt_off, int* __restrict__ bsum)
{
    __shared__ int sh[256];
    const int t = threadIdx.x, b = blockIdx.x;
    const int i = b*256 + t;
    const int v = (i < NN) ? cnt[i] : 0;
    sh[t] = v;
    __syncthreads();
    #pragma unroll
    for (int d = 1; d < 256; d <<= 1){
        const int u = (t >= d) ? sh[t-d] : 0;
        __syncthreads();
        sh[t] += u;
        __syncthreads();
    }
    if (i < NN) tgt_off[i] = sh[t] - v;
    if (t == 255) bsum[b] = sh[255];
}
__global__ __launch_bounds__(128) void k_scan2(const int* __restrict__ bsum,
    int* __restrict__ bbase, int* __restrict__ tgt_off)
{
    __shared__ int sh[128];
    const int t = threadIdx.x;
    const int v = (t < SCB) ? bsum[t] : 0;
    sh[t] = v;
    __syncthreads();
    #pragma unroll
    for (int d = 1; d < 128; d <<= 1){
        const int u = (t >= d) ? sh[t-d] : 0;
        __syncthreads();
        sh[t] += u;
        __syncthreads();
    }
    if (t < SCB) bbase[t] = sh[t] - v;
    if (t == 0) tgt_off[NN] = NE;
}
__global__ __launch_bounds__(256) void k_scan3(int* __restrict__ tgt_off,
    const int* __restrict__ bbase, int* __restrict__ binCur)
{
    const int i = blockIdx.x*256 + threadIdx.x;
    if (i >= NN) return;
    const int o = tgt_off[i] + bbase[blockIdx.x];
    tgt_off[i] = o;
    binCur[i] = o;
}
__global__ void k_csr_scatter(const int* __restrict__ ei, const int* __restrict__ etype,
    const int* __restrict__ etime, const int* __restrict__ ntype,
    int* __restrict__ binCur, int* __restrict__ src_s, int* __restrict__ combo_s,
    int* __restrict__ eid_s)
{
    int e = blockIdx.x*256 + threadIdx.x;
    if (e >= NE) return;
    const int tgt = ei[NE+e], r = etype[e], src = ei[e];
    const int pos = atomicAdd(&binCur[tgt], 1);
    src_s[pos] = src;
    combo_s[pos] = (etime[e]*NT + ntype[src]) | (r << 12);
    eid_s[pos] = e;
}
__global__ void k_tgtmap(const int* __restrict__ tgt_off, int* __restrict__ tgt_srt)
{
    const int n = blockIdx.x*256 + threadIdx.x;
    if (n >= NN) return;
    const int e0 = tgt_off[n], e1 = tgt_off[n+1];
    for (int j = e0; j < e1; j++) tgt_srt[j] = n;
}

// ---------- weight pre-pack (merged): 36 big 256x256 mats -> frag-major f16 ----------
__global__ __launch_bounds__(256) void k_w2f16_big(
    const float* __restrict__ adaptW, const float* __restrict__ qW, const float* __restrict__ kW,
    const float* __restrict__ vW, const float* __restrict__ aW, _Float16* __restrict__ out)
{
    const int y = blockIdx.y;
    const float* src; int m;
    if (y < 4){ src = adaptW; m = y; }
    else if (y < 12){ src = qW; m = y-4; }
    else if (y < 20){ src = kW; m = y-12; }
    else if (y < 28){ src = vW; m = y-20; }
    else { src = aW; m = y-28; }
    const float* ip = src + (size_t)m*65536;
    _Float16* op = out + (size_t)y*65536;
    const int tid4 = blockIdx.x*256 + threadIdx.x;
    const int k4 = tid4 >> 8, c = tid4 & 255;
    f16x4 hv;
    #pragma unroll
    for (int j = 0; j < 4; j++)
        hv[j] = (_Float16)ip[(size_t)(((k4*4 + j) << 8) + c)];
    *reinterpret_cast<f16x4*>(&op[(size_t)tid4 * 4]) = hv;
}
// 256 rel 32x32 mats (att then msg) -> frag-major f16
__global__ __launch_bounds__(256) void k_w2f16_rel(
    const float* __restrict__ attW, const float* __restrict__ msgW, _Float16* __restrict__ out)
{
    const int y = blockIdx.y;
    const float* ip = (y < 128) ? (attW + (size_t)y*1024) : (msgW + (size_t)(y-128)*1024);
    _Float16* op = out + (size_t)y*1024;
    const int tid4 = threadIdx.x;
    const int k4 = tid4 >> 5, c = tid4 & 31;
    f16x4 hv;
    #pragma unroll
    for (int j = 0; j < 4; j++)
        hv[j] = (_Float16)ip[(size_t)(((k4*4 + j) << 5) + c)];
    *reinterpret_cast<f16x4*>(&op[(size_t)tid4 * 4]) = hv;
}

// ---------- act GEMM: out = act(in @ W[t] + b[t]); x stored f16 ----------
__global__ __launch_bounds__(256) void k_x(
    const float* __restrict__ inF, const _Float16* __restrict__ inH,
    const _Float16* __restrict__ Wb, const float* __restrict__ bb, void* __restrict__ out,
    const int* __restrict__ nbucket, const int* __restrict__ noff,
    const int* __restrict__ tlist, const int* __restrict__ tcount,
    int mode, int oh, const float* __restrict__ skipv, const _Float16* __restrict__ xoldH)
{
    if ((int)blockIdx.x >= *tcount) return;
    const int ent = tlist[blockIdx.x];
    const int t = ent >> 20, rowTile = ent & 0xFFFFF;
    const int start = noff[t], cnt = noff[t+1] - start;

    const int tid = threadIdx.x;
    const int w = tid >> 6, lane = tid & 63;
    const int lrow = lane & 15, lgrp = lane >> 4;

    __shared__ _Float16 Al[32][260];
    __shared__ int nid[32];

    if (tid < 32){
        const int gr = rowTile*32 + tid;
        nid[tid] = (gr < cnt) ? nbucket[start + gr] : -1;
    }
    __syncthreads();
    {
        const int r = tid >> 3;
        const int arow = nid[r];
        if (inH){
            const _Float16* ap = (arow >= 0) ? (inH + (size_t)arow*HD) : nullptr;
            #pragma unroll
            for (int j = 0; j < 8; j++){
                const int f4 = (tid & 7) + j*8;
                f16x4 hv = {0,0,0,0};
                if (ap) hv = *reinterpret_cast<const f16x4*>(ap + f4*4);
                *reinterpret_cast<f16x4*>(&Al[r][f4*4]) = hv;
            }
        } else {
            const float* ap = (arow >= 0) ? (inF + (size_t)arow*HD) : nullptr;
            #pragma unroll
            for (int j = 0; j < 8; j++){
                const int f4 = (tid & 7) + j*8;
                float4 v = make_float4(0.f,0.f,0.f,0.f);
                if (ap) v = *reinterpret_cast<const float4*>(ap + f4*4);
                f16x4 hv;
                hv[0]=(_Float16)v.x; hv[1]=(_Float16)v.y; hv[2]=(_Float16)v.z; hv[3]=(_Float16)v.w;
                *reinterpret_cast<f16x4*>(&Al[r][f4*4]) = hv;
            }
        }
    }
    __syncthreads();

    float sk = 0.f;
    if (mode == 2) sk = 1.f/(1.f + __expf(-skipv[t]));

    const _Float16* W = Wb + (size_t)t*HD*HD;
    const float* bias = bb + (size_t)t*HD;
    f32x4v acc[4][2];
    #pragma unroll
    for (int cs = 0; cs < 4; cs++){
        acc[cs][0] = (f32x4v){0.f,0.f,0.f,0.f};
        acc[cs][1] = (f32x4v){0.f,0.f,0.f,0.f};
    }
    #pragma unroll 4
    for (int kc = 0; kc < 16; kc++){
        f16x4 bf[4];
        #pragma unroll
        for (int cs = 0; cs < 4; cs++)
            bf[cs] = *reinterpret_cast<const f16x4*>(
                &W[(size_t)((kc*4 + lgrp)*HD + w*64 + cs*16 + lrow)*4]);
        const f16x4 af0 = *reinterpret_cast<const f16x4*>(&Al[lrow][kc*16 + lgrp*4]);
        const f16x4 af1 = *reinterpret_cast<const f16x4*>(&Al[16 + lrow][kc*16 + lgrp*4]);
        #pragma unroll
        for (int cs = 0; cs < 4; cs++){
            acc[cs][0] = __builtin_amdgcn_mfma_f32_16x16x16f16(af0, bf[cs], acc[cs][0], 0,0,0);
            acc[cs][1] = __builtin_amdgcn_mfma_f32_16x16x16f16(af1, bf[cs], acc[cs][1], 0,0,0);
        }
    }
    #pragma unroll
    for (int cs = 0; cs < 4; cs++){
        const int col = w*64 + cs*16 + lrow;
        const float bcol = bias[col];
        #pragma unroll
        for (int rt = 0; rt < 2; rt++){
            #pragma unroll
            for (int i = 0; i < 4; i++){
                const int lr = rt*16 + lgrp*4 + i;
                const int gr = rowTile*32 + lr;
                if (gr >= cnt) continue;
                const int node = nid[lr];
                float v = acc[cs][rt][i] + bcol;
                if (mode == 1) v = tanhf(v);
                else if (mode == 2){
                    const float xo = (float)xoldH[(size_t)node*HD + col];
                    v = v*sk + xo*(1.f - sk);
                }
                if (oh) ((_Float16*)out)[(size_t)node*HD + col] = (_Float16)v;
                else    ((float*)out)[(size_t)node*HD + col] = v;
            }
        }
    }
}

// ---------- QKV GEMM split by blockIdx.y; LDS-staged coalesced f16x8 output ----------
__global__ __launch_bounds__(256) void k_qkv(
    const _Float16* __restrict__ xh,
    const _Float16* __restrict__ Wq, const float* __restrict__ bq, _Float16* __restrict__ oq,
    const _Float16* __restrict__ Wk, const float* __restrict__ bk, _Float16* __restrict__ okk,
    const _Float16* __restrict__ Wv, const float* __restrict__ bv, _Float16* __restrict__ ov,
    const int* __restrict__ nbucket, const int* __restrict__ noff,
    const int* __restrict__ tlist, const int* __restrict__ tcount)
{
    if ((int)blockIdx.x >= *tcount) return;
    const int ent = tlist[blockIdx.x];
    const int t = ent >> 20, rowTile = ent & 0xFFFFF;
    const int start = noff[t], cnt = noff[t+1] - start;
    const int sel = blockIdx.y;
    const _Float16* Wb = (sel==0 ? Wq : (sel==1 ? Wk : Wv));
    const float* bb = (sel==0 ? bq : (sel==1 ? bk : bv));
    _Float16* out = (sel==0 ? oq : (sel==1 ? okk : ov));

    const int tid = threadIdx.x;
    const int w = tid >> 6, lane = tid & 63;
    const int lrow = lane & 15, lgrp = lane >> 4;

    __shared__ _Float16 Al[32][260];
    __shared__ __align__(16) _Float16 Ol[32][264];
    __shared__ int nid[32];

    if (tid < 32){
        const int gr = rowTile*32 + tid;
        nid[tid] = (gr < cnt) ? nbucket[start + gr] : -1;
    }
    __syncthreads();
    {
        const int r = tid >> 3;
        const int arow = nid[r];
        const _Float16* ap = (arow >= 0) ? (xh + (size_t)arow*HD) : nullptr;
        #pragma unroll
        for (int j = 0; j < 8; j++){
            const int f4 = (tid & 7) + j*8;
            f16x4 hv = {0,0,0,0};
            if (ap) hv = *reinterpret_cast<const f16x4*>(ap + f4*4);
            *reinterpret_cast<f16x4*>(&Al[r][f4*4]) = hv;
        }
    }
    __syncthreads();

    const _Float16* W = Wb + (size_t)t*HD*HD;
    const float* bias = bb + (size_t)t*HD;
    f32x4v acc[4][2];
    #pragma unroll
    for (int cs = 0; cs < 4; cs++){
        acc[cs][0] = (f32x4v){0.f,0.f,0.f,0.f};
        acc[cs][1] = (f32x4v){0.f,0.f,0.f,0.f};
    }
    #pragma unroll 4
    for (int kc = 0; kc < 16; kc++){
        f16x4 bf[4];
        #pragma unroll
        for (int cs = 0; cs < 4; cs++)
            bf[cs] = *reinterpret_cast<const f16x4*>(
                &W[(size_t)((kc*4 + lgrp)*HD + w*64 + cs*16 + lrow)*4]);
        const f16x4 af0 = *reinterpret_cast<const f16x4*>(&Al[lrow][kc*16 + lgrp*4]);
        const f16x4 af1 = *reinterpret_cast<const f16x4*>(&Al[16 + lrow][kc*16 + lgrp*4]);
        #pragma unroll
        for (int cs = 0; cs < 4; cs++){
            acc[cs][0] = __builtin_amdgcn_mfma_f32_16x16x16f16(af0, bf[cs], acc[cs][0], 0,0,0);
            acc[cs][1] = __builtin_amdgcn_mfma_f32_16x16x16f16(af1, bf[cs], acc[cs][1], 0,0,0);
        }
    }
    // stage output tile in LDS (2B writes, conflict-benign), then coalesced flush
    #pragma unroll
    for (int cs = 0; cs < 4; cs++){
        const int col = w*64 + cs*16 + lrow;
        const float bcol = bias[col];
        #pragma unroll
        for (int rt = 0; rt < 2; rt++){
            #pragma unroll
            for (int i = 0; i < 4; i++){
                const int lr = rt*16 + lgrp*4 + i;
                Ol[lr][col] = (_Float16)(acc[cs][rt][i] + bcol);
            }
        }
    }
    __syncthreads();
    {
        const int fcb = tid & 31;           // 16B chunk within row
        #pragma unroll
        for (int it = 0; it < 4; it++){
            const int rr = (tid >> 5) + it*8;
            const int node = nid[rr];
            if (node < 0) continue;
            const f16x8 v = *reinterpret_cast<const f16x8*>(&Ol[rr][fcb*8]);
            *reinterpret_cast<f16x8*>(&out[(size_t)node*HD + fcb*8]) = v;
        }
    }
}

// ---------- small row GEMM: rteP = rte_emb @ rte_W + rte_b (f32 out) ----------
__global__ __launch_bounds__(256) void k_row_gemm(
    const float* __restrict__ A, const float* __restrict__ W, const float* __restrict__ bias,
    float* __restrict__ C)
{
    const int row = blockIdx.x, d = threadIdx.x;
    __shared__ float ar[HD];
    ar[d] = A[(size_t)row*HD + d];
    __syncthreads();
    float acc = bias[d];
    #pragma unroll 8
    for (int k=0;k<HD;k++) acc = fmaf(ar[k], W[(size_t)k*HD + d], acc);
    C[(size_t)row*HD + d] = acc;
}
__global__ __launch_bounds__(256) void k_row_gemm2(
    const float* __restrict__ A, const float* __restrict__ kWb, const float* __restrict__ vWb,
    _Float16* __restrict__ Kc, _Float16* __restrict__ Vc)
{
    const int row = blockIdx.x, ty = blockIdx.y, d = threadIdx.x;
    const float* W = ((blockIdx.z == 0) ? kWb : vWb) + (size_t)ty*HD*HD;
    _Float16* C = (blockIdx.z == 0) ? Kc : Vc;
    __shared__ float ar[HD];
    ar[d] = A[(size_t)row*HD + d];
    __syncthreads();
    float acc = 0.f;
    #pragma unroll 8
    for (int k=0;k<HD;k++) acc = fmaf(ar[k], W[(size_t)k*HD + d], acc);
    C[(size_t)row*(NT*HD) + ty*HD + d] = (_Float16)acc;
}

// ---------- MFMA dual fold (combo tables): grid (nbx, NR, 2) ----------
__global__ __launch_bounds__(256) void k_fold2(
    const _Float16* __restrict__ INa, const _Float16* __restrict__ MATa, _Float16* __restrict__ OUTa,
    const _Float16* __restrict__ INb, const _Float16* __restrict__ MATb, _Float16* __restrict__ OUTb,
    int M, int nbx)
{
    const int r = blockIdx.y;
    const _Float16* IN = blockIdx.z ? INb : INa;
    const _Float16* MATF = blockIdx.z ? MATb : MATa;
    _Float16* OUT = blockIdx.z ? OUTb : OUTa;
    const int lane = threadIdx.x & 63, w = threadIdx.x >> 6;
    const int lrow = lane & 15, lgrp = lane >> 4;
    f16x4 b[NH][2][2];
    const _Float16* Mr = MATF + (size_t)r*NH*1024;
    #pragma unroll
    for (int h = 0; h < NH; h++)
      #pragma unroll
      for (int kb = 0; kb < 2; kb++)
        #pragma unroll
        for (int hf = 0; hf < 2; hf++)
            b[h][kb][hf] = *reinterpret_cast<const f16x4*>(
                &Mr[(size_t)h*1024 + (size_t)(((kb*4 + lgrp)*32) + hf*16 + lrow)*4]);
    const int ntiles = M >> 4;
    for (int t = (int)blockIdx.x*4 + w; t < ntiles; t += nbx*4){
        const int row0 = t*16;
        const _Float16* inrow = IN + (size_t)(row0 + lrow)*HD;
        f16x4 a[NH][2];
        #pragma unroll
        for (int h = 0; h < NH; h++)
          #pragma unroll
          for (int kb = 0; kb < 2; kb++)
              a[h][kb] = *reinterpret_cast<const f16x4*>(&inrow[h*32 + kb*16 + lgrp*4]);
        #pragma unroll
        for (int h = 0; h < NH; h++){
          #pragma unroll
          for (int hf = 0; hf < 2; hf++){
              f32x4v acc = {0.f,0.f,0.f,0.f};
              acc = __builtin_amdgcn_mfma_f32_16x16x16f16(a[h][0], b[h][0][hf], acc, 0,0,0);
              acc = __builtin_amdgcn_mfma_f32_16x16x16f16(a[h][1], b[h][1][hf], acc, 0,0,0);
              #pragma unroll
              for (int i = 0; i < 4; i++){
                  const int rr = lgrp*4 + i;
                  OUT[((size_t)(row0+rr)*NR + r)*HD + h*32 + hf*16 + lrow] = (_Float16)acc[i];
              }
          }
        }
    }
}

// ---------- node fold, XCD-aware + XOR-swizzled 32KB LDS tile (5 blocks/CU) ----------
// swizzle: halfword offset o = rr*256+col  ->  o ^ ((rr&7)<<3).  XOR touches bits 3-5
// only, so the f16x8 flush read (fcb*8-aligned) stays contiguous and 16B-aligned.
__global__ __launch_bounds__(256) void k_fold2x(
    const _Float16* __restrict__ INa, const _Float16* __restrict__ MATa, _Float16* __restrict__ OUTa,
    const _Float16* __restrict__ INb, const _Float16* __restrict__ MATb, _Float16* __restrict__ OUTb)
{
    const int bid = blockIdx.x;
    const int xcd = bid & 7;
    const int s = bid >> 3;                 // 0..159
    const int tr = xcd*10 + (s >> 4);       // tile-range 0..79 (79 invalid)
    if (tr >= FOLDN) return;
    const int item = s & 15;
    const int r = item & 7;
    const _Float16* IN = (item >> 3) ? INb : INa;
    const _Float16* MATF = (item >> 3) ? MATb : MATa;
    _Float16* OUT = (item >> 3) ? OUTb : OUTa;

    const int lane = threadIdx.x & 63, w = threadIdx.x >> 6;
    const int lrow = lane & 15, lgrp = lane >> 4;

    __shared__ __align__(16) _Float16 tile[4][4096];   // 16x256 per wave, 32KB total

    f16x4 b[NH][2][2];
    const _Float16* Mr = MATF + (size_t)r*NH*1024;
    #pragma unroll
    for (int h = 0; h < NH; h++)
      #pragma unroll
      for (int kb = 0; kb < 2; kb++)
        #pragma unroll
        for (int hf = 0; hf < 2; hf++)
            b[h][kb][hf] = *reinterpret_cast<const f16x4*>(
                &Mr[(size_t)h*1024 + (size_t)(((kb*4 + lgrp)*32) + hf*16 + lrow)*4]);

    const int frow = lane >> 5;      // flush: row parity (2 rows per store instr)
    const int fcb  = lane & 31;      // flush: 16B chunk within row
    const int ntiles = NN >> 4;      // 1250
    for (int t = tr*4 + w; t < ntiles; t += FOLDN*4){
        const int row0 = t*16;
        const _Float16* inrow = IN + (size_t)(row0 + lrow)*HD;
        f16x4 a[NH][2];
        #pragma unroll
        for (int h = 0; h < NH; h++)
          #pragma unroll
          for (int kb = 0; kb < 2; kb++)
              a[h][kb] = *reinterpret_cast<const f16x4*>(&inrow[h*32 + kb*16 + lgrp*4]);
        #pragma unroll
        for (int h = 0; h < NH; h++){
          #pragma unroll
          for (int hf = 0; hf < 2; hf++){
              f32x4v acc = {0.f,0.f,0.f,0.f};
              acc = __builtin_amdgcn_mfma_f32_16x16x16f16(a[h][0], b[h][0][hf], acc, 0,0,0);
              acc = __builtin_amdgcn_mfma_f32_16x16x16f16(a[h][1], b[h][1][hf], acc, 0,0,0);
              const int col = h*32 + hf*16 + lrow;
              #pragma unroll
              for (int i = 0; i < 4; i++){
                  const int rr = lgrp*4 + i;
                  tile[w][(rr*256 + col) ^ ((rr & 7) << 3)] = (_Float16)acc[i];
              }
          }
        }
        // intra-wave LDS write->read ordering (per-wave tile; no cross-wave dep)
        asm volatile("s_waitcnt lgkmcnt(0)" ::: "memory");
        __builtin_amdgcn_sched_barrier(0);
        #pragma unroll
        for (int jj = 0; jj < 8; jj++){
            const int rr = jj*2 + frow;
            const f16x8 v = *reinterpret_cast<const f16x8*>(
                &tile[w][(rr*256 + fcb*8) ^ ((rr & 7) << 3)]);
            *reinterpret_cast<f16x8*>(&OUT[((size_t)(row0+rr)*NR + r)*HD + fcb*8]) = v;
        }
        asm volatile("s_waitcnt lgkmcnt(0)" ::: "memory");
        __builtin_amdgcn_sched_barrier(0);
    }
}

// ---------- fused edge pass, software-pipelined gathers ----------
__global__ __launch_bounds__(256) void k_edge(
    const _Float16* __restrict__ q0, const _Float16* __restrict__ kA, const _Float16* __restrict__ KcA,
    const _Float16* __restrict__ vM, const _Float16* __restrict__ VcM,
    const float* __restrict__ relP,
    const int* __restrict__ tgt_off, const int* __restrict__ src_s, const int* __restrict__ combo_s,
    _Float16* __restrict__ agg,
    float* __restrict__ s_arr, float* __restrict__ mbuf, float* __restrict__ lbuf, int store_s)
{
    const int n = blockIdx.x*4 + (threadIdx.x >> 6);
    if (n >= NN) return;
    const int lane = threadIdx.x & 63;
    const int h = lane >> 3, c4 = (lane & 7) << 2;
    const int col = h*32 + c4;
    const int e0 = tgt_off[n], e1 = tgt_off[n+1];

    const f16x4 qh = *reinterpret_cast<const f16x4*>(&q0[(size_t)n*HD + col]);
    const float q0v = (float)qh[0], q1v = (float)qh[1], q2v = (float)qh[2], q3v = (float)qh[3];
    float m = -INFINITY, l = 0.f;
    float a0=0.f, a1=0.f, a2=0.f, a3=0.f;

    if (e0 < e1){
        int cwA = combo_s[e0];
        const int srcA0 = src_s[e0];
        const int rA0 = cwA >> 12, comboA0 = cwA & 0xFFF;
        f16x4 kaA = *reinterpret_cast<const f16x4*>(&kA [((size_t)srcA0*NR + rA0)*HD + col]);
        f16x4 kcA = *reinterpret_cast<const f16x4*>(&KcA[((size_t)comboA0*NR + rA0)*HD + col]);
        f16x4 vmA = *reinterpret_cast<const f16x4*>(&vM [((size_t)srcA0*NR + rA0)*HD + col]);
        f16x4 vcA = *reinterpret_cast<const f16x4*>(&VcM[((size_t)comboA0*NR + rA0)*HD + col]);
        const int j1 = min(e0+1, e1-1);
        int srcB = src_s[j1], cwB = combo_s[j1];

        for (int j = e0; j < e1; j++){
            // prefetch rows for j+1 (clamped -> always valid)
            const int rB = cwB >> 12, comboB = cwB & 0xFFF;
            const size_t offSB = ((size_t)srcB*NR + rB)*HD + col;
            const size_t offCB = ((size_t)comboB*NR + rB)*HD + col;
            const f16x4 kaN = *reinterpret_cast<const f16x4*>(&kA [offSB]);
            const f16x4 kcN = *reinterpret_cast<const f16x4*>(&KcA[offCB]);
            const f16x4 vmN = *reinterpret_cast<const f16x4*>(&vM [offSB]);
            const f16x4 vcN = *reinterpret_cast<const f16x4*>(&VcM[offCB]);
            // prefetch indices for j+2 (clamped)
            const int jn = min(j+2, e1-1);
            const int srcN = src_s[jn], cwN = combo_s[jn];

            // compute with current (A) regs
            const int r = cwA >> 12;
            float s = q0v*((float)kaA[0]+(float)kcA[0])
                    + q1v*((float)kaA[1]+(float)kcA[1])
                    + q2v*((float)kaA[2]+(float)kcA[2])
                    + q3v*((float)kaA[3]+(float)kcA[3]);
            s += __shfl_xor(s, 1); s += __shfl_xor(s, 2); s += __shfl_xor(s, 4);
            s *= relP[r*NH + h] * INV_SQRT_DK;
            if (store_s && (lane & 7) == 0) s_arr[(size_t)j*NH + h] = s;
            const float mn = fmaxf(m, s);
            const float sc = __expf(m - mn);     // first edge: m=-inf -> 0
            const float p  = __expf(s - mn);
            l = l*sc + p;
            m = mn;
            a0 = a0*sc + p*((float)vmA[0] + (float)vcA[0]);
            a1 = a1*sc + p*((float)vmA[1] + (float)vcA[1]);
            a2 = a2*sc + p*((float)vmA[2] + (float)vcA[2]);
            a3 = a3*sc + p*((float)vmA[3] + (float)vcA[3]);

            // rotate pipeline
            cwA = cwB;
            kaA = kaN; kcA = kcN; vmA = vmN; vcA = vcN;
            srcB = srcN; cwB = cwN;
        }
    }
    const float inv = (l > 0.f) ? 1.f/l : 0.f;
    a0 *= inv; a1 *= inv; a2 *= inv; a3 *= inv;
    f16x4 o;
    o[0] = (_Float16)(0.5f*a0*(1.f + erff(a0*0.70710678118654752f)));
    o[1] = (_Float16)(0.5f*a1*(1.f + erff(a1*0.70710678118654752f)));
    o[2] = (_Float16)(0.5f*a2*(1.f + erff(a2*0.70710678118654752f)));
    o[3] = (_Float16)(0.5f*a3*(1.f + erff(a3*0.70710678118654752f)));
    *reinterpret_cast<f16x4*>(&agg[(size_t)n*HD + col]) = o;
    if (store_s && (lane & 7) == 0){
        mbuf[(size_t)n*NH + h] = m;
        lbuf[(size_t)n*NH + h] = l;
    }
}

// ---------- alpha output from stored scores (last layer only) ----------
__global__ void k_alpha(const float* __restrict__ s_arr, const int* __restrict__ eid_s,
                        const float* __restrict__ mbuf, const float* __restrict__ lbuf,
                        const int* __restrict__ tgt_srt, float* __restrict__ out_att)
{
    int i = blockIdx.x*256 + threadIdx.x;
    if (i >= NE*NH) return;
    const int j = i >> 3, h = i & 7;
    const int t = tgt_srt[j];
    const float a = __expf(s_arr[i] - mbuf[(size_t)t*NH + h]) / lbuf[(size_t)t*NH + h];
    out_att[(size_t)eid_s[j]*NH + h] = a;
}

extern "C" void kernel_launch(void* const* d_in, const int* in_sizes, int n_in,
                              void* d_out, int out_size, void* d_ws, size_t ws_size,
                              hipStream_t stream)
{
    const float* node_feature = (const float*)d_in[0];
    const int*   node_type    = (const int*)d_in[1];
    const int*   edge_time    = (const int*)d_in[2];
    const int*   edge_index   = (const int*)d_in[3];
    const int*   edge_type    = (const int*)d_in[4];
    const float* adapt_W = (const float*)d_in[5];
    const float* adapt_b = (const float*)d_in[6];
    const float* k_W = (const float*)d_in[7];
    const float* k_b = (const float*)d_in[8];
    const float* q_W = (const float*)d_in[9];
    const float* q_b = (const float*)d_in[10];
    const float* v_W = (const float*)d_in[11];
    const float* v_b = (const float*)d_in[12];
    const float* a_W = (const float*)d_in[13];
    const float* a_b = (const float*)d_in[14];
    const float* rel_pri = (const float*)d_in[15];
    const float* rel_att = (const float*)d_in[16];
    const float* rel_msg = (const float*)d_in[17];
    const float* skip  = (const float*)d_in[18];
    const float* rte_W = (const float*)d_in[19];
    const float* rte_b = (const float*)d_in[20];
    const float* rte_emb = (const float*)d_in[21];

    char* wp = (char*)d_ws;
    auto alloc_f = [&](size_t n)->float*{ float* p=(float*)wp; wp += n*sizeof(float); return p; };
    auto alloc_i = [&](size_t n)->int*  { int*   p=(int*)wp;   wp += n*sizeof(int);   return p; };
    auto alloc_h = [&](size_t n)->_Float16*{ _Float16* p=(_Float16*)wp; wp += n*sizeof(_Float16); return p; };
    _Float16* xh0 = alloc_h((size_t)NN*HD);
    _Float16* xh1 = alloc_h((size_t)NN*HD);
    _Float16* q0h = alloc_h((size_t)NN*HD);
    _Float16* k0h = alloc_h((size_t)NN*HD);
    _Float16* v0h = alloc_h((size_t)NN*HD);
    _Float16* aggh= alloc_h((size_t)NN*HD);
    float* s_arr = alloc_f((size_t)NE*NH);
    float* mbuf  = alloc_f((size_t)NN*NH);
    float* lbuf  = alloc_f((size_t)NN*NH);
    float* rteP  = alloc_f((size_t)MAXL*HD);
    _Float16* Kch = alloc_h((size_t)MAXL*NT*HD);
    _Float16* Vch = alloc_h((size_t)MAXL*NT*HD);
    _Float16* kavm = alloc_h((size_t)NN*NR*HD);            // att node table
    _Float16* vmh  = alloc_h((size_t)NN*NR*HD);            // msg node table
    _Float16* kcaA0 = alloc_h((size_t)MAXL*NT*NR*HD);
    _Float16* kcaA1 = alloc_h((size_t)MAXL*NT*NR*HD);
    _Float16* kcaM0 = alloc_h((size_t)MAXL*NT*NR*HD);
    _Float16* kcaM1 = alloc_h((size_t)MAXL*NT*NR*HD);
    _Float16* wF   = alloc_h((size_t)36*65536);
    _Float16* relF = alloc_h((size_t)256*1024);
    int* nbucket = alloc_i(NN);
    int* nhist   = alloc_i(HBLK*NT);
    int* nbase   = alloc_i(HBLK*NT);
    int* noff    = alloc_i(8);
    int* tlist   = alloc_i(TMAX);
    int* tcount  = alloc_i(8);
    int* cnt     = alloc_i(NN);
    int* bsum    = alloc_i(SCB);
    int* bbase   = alloc_i(SCB);
    int* binCur  = alloc_i(NN);
    int* tgt_off = alloc_i(NN+1);
    int* src_s   = alloc_i(NE);
    int* combo_s = alloc_i(NE);
    int* eid_s   = alloc_i(NE);
    int* tgt_srt = alloc_i(NE);

    const _Float16* adaptF = wF;
    const _Float16* qF = wF + (size_t)4*65536;
    const _Float16* kF = wF + (size_t)12*65536;
    const _Float16* vF = wF + (size_t)20*65536;
    const _Float16* aF = wF + (size_t)28*65536;
    const _Float16* relAF = relF;
    const _Float16* relMF = relF + (size_t)128*1024;

    float* out_att = (float*)d_out;
    float* out_x   = (float*)d_out + (size_t)NE*NH;

    const dim3 gFoldC2(FOLDC, NR, 2);
    const dim3 gQKV(TMAX, 3);
    const int gFoldX = 1280;
    const int gE256 = (NE + 255)/256;
    const int gEH = (NE*NH + 255)/256;
    const int gN256 = (NN + 255)/256;
    const int gEg = (NN + 3)/4;

    // weight pre-pack
    k_w2f16_big<<<dim3(64,36),256,0,stream>>>(adapt_W, q_W, k_W, v_W, a_W, wF);
    k_w2f16_rel<<<dim3(1,256),256,0,stream>>>(rel_att, rel_msg, relF);

    // node buckets + tile list
    k_nhist<<<HBLK,256,0,stream>>>(node_type, nhist);
    k_nscan<<<1,64,0,stream>>>(nhist, noff, nbase, tlist, tcount);
    k_nscatter<<<HBLK,256,0,stream>>>(node_type, nbase, nbucket);

    // edge CSR sorted by tgt
    k_zero_bins<<<SCB,256,0,stream>>>(cnt);
    k_csr_hist<<<gE256,256,0,stream>>>(edge_index, cnt);
    k_scan1<<<SCB,256,0,stream>>>(cnt, tgt_off, bsum);
    k_scan2<<<1,128,0,stream>>>(bsum, bbase, tgt_off);
    k_scan3<<<SCB,256,0,stream>>>(tgt_off, bbase, binCur);
    k_csr_scatter<<<gE256,256,0,stream>>>(edge_index, edge_type, edge_time, node_type,
                                          binCur, src_s, combo_s, eid_s);
    k_tgtmap<<<gN256,256,0,stream>>>(tgt_off, tgt_srt);

    // preamble: layer-invariant combo tables (merged att+msg folds)
    {
        k_row_gemm<<<MAXL,256,0,stream>>>(rte_emb, rte_W, rte_b, rteP);
        k_row_gemm2<<<dim3(MAXL,NT,2),256,0,stream>>>(rteP, k_W, v_W, Kch, Vch);
        k_fold2<<<gFoldC2,256,0,stream>>>(Kch, relAF, kcaA0, Vch, relMF, kcaM0, MAXL*NT, FOLDC);
        k_row_gemm<<<MAXL,256,0,stream>>>(rte_emb, rte_W + (size_t)HD*HD, rte_b + HD, rteP);
        k_row_gemm2<<<dim3(MAXL,NT,2),256,0,stream>>>(rteP, k_W + (size_t)NT*HD*HD,
                                                      v_W + (size_t)NT*HD*HD, Kch, Vch);
        k_fold2<<<gFoldC2,256,0,stream>>>(Kch, relAF + (size_t)NR*NH*1024, kcaA1,
                                          Vch, relMF + (size_t)NR*NH*1024, kcaM1, MAXL*NT, FOLDC);
    }

    // adapt -> xh0 (f16), then split QKV(l=0)
    k_x<<<TMAX,256,0,stream>>>(node_feature, nullptr, adaptF, adapt_b, xh0,
                               nbucket, noff, tlist, tcount, 1, 1, nullptr, nullptr);
    k_qkv<<<gQKV,256,0,stream>>>(xh0, qF, q_b, q0h, kF, k_b, k0h, vF, v_b, v0h,
                                 nbucket, noff, tlist, tcount);

    for (int l = 0; l < NL; l++){
        const _Float16* rAF = relAF + (size_t)l*NR*NH*1024;
        const _Float16* rMF = relMF + (size_t)l*NR*NH*1024;
        const _Float16* kcaA = (l == 0) ? kcaA0 : kcaA1;
        const _Float16* kcaM = (l == 0) ? kcaM0 : kcaM1;
        const int store_s = (l == NL-1) ? 1 : 0;
        // merged node folds (att + msg), XCD-aware mapping + coalesced stores
        k_fold2x<<<gFoldX,256,0,stream>>>(k0h, rAF, kavm, v0h, rMF, vmh);
        // fused score + online softmax + aggregate + gelu (pipelined gathers)
        k_edge<<<gEg,256,0,stream>>>(q0h, kavm, kcaA, vmh, kcaM,
                                     rel_pri + (size_t)l*NR*NH,
                                     tgt_off, src_s, combo_s, aggh,
                                     s_arr, mbuf, lbuf, store_s);
        if (store_s)
            k_alpha<<<gEH,256,0,stream>>>(s_arr, eid_s, mbuf, lbuf, tgt_srt, out_att);
        // aW(l); next-layer x + QKV if not last
        if (l == 0){
            k_x<<<TMAX,256,0,stream>>>(nullptr, aggh, aF, a_b, xh1,
                                       nbucket, noff, tlist, tcount, 2, 1, skip, xh0);
            k_qkv<<<gQKV,256,0,stream>>>(xh1, qF + (size_t)NT*HD*HD, q_b + (size_t)NT*HD, q0h,
                                         kF + (size_t)NT*HD*HD, k_b + (size_t)NT*HD, k0h,
                                         vF + (size_t)NT*HD*HD, v_b + (size_t)NT*HD, v0h,
                                         nbucket, noff, tlist, tcount);
        } else {
            k_x<<<TMAX,256,0,stream>>>(nullptr, aggh, aF + (size_t)NT*HD*HD, a_b + (size_t)NT*HD,
                                       out_x, nbucket, noff, tlist, tcount, 2, 0, skip + NT, xh1);
        }
    }
}

// Round 32
// 487.548 us; speedup vs baseline: 1.0128x; 1.0128x over previous
//
#include <hip/hip_runtime.h>
#include <hip/hip_fp16.h>

#define NN    20000
#define NE    150000
#define HD    256
#define NT    4
#define NR    8
#define NH    8
#define DKq   32
#define NL    2
#define MAXL  240
#define HBLK  256
#define SCB   ((NN + 255)/256)
#define TMAX  632
#define FOLDC 15
#define FTR   64              /* node-fold tile-ranges: 8 XCD x 8 */
#define INV_SQRT_DK 0.17677669529663687f

typedef _Float16 f16x4 __attribute__((ext_vector_type(4)));
typedef _Float16 f16x8 __attribute__((ext_vector_type(8)));
typedef float    f32x4v __attribute__((ext_vector_type(4)));

// ---------- node bucketing (by type) + compact 32-row tile list ----------
__global__ __launch_bounds__(256) void k_nhist(const int* __restrict__ ntype, int* __restrict__ nhist)
{
    __shared__ int h[NT];
    const int tid = threadIdx.x, b = blockIdx.x;
    if (tid < NT) h[tid] = 0;
    __syncthreads();
    const int cn = (NN + HBLK-1)/HBLK;
    const int nEnd = min((b+1)*cn, NN);
    for (int i = b*cn + tid; i < nEnd; i += 256) atomicAdd(&h[ntype[i]], 1);
    __syncthreads();
    if (tid < NT) nhist[b*NT + tid] = h[tid];
}
__global__ void k_nscan(const int* __restrict__ nhist, int* __restrict__ noff, int* __restrict__ nbase,
                        int* __restrict__ tlist, int* __restrict__ tcount)
{
    __shared__ int tot[NT];
    const int tid = threadIdx.x;
    if (tid < NT){
        int s = 0;
        for (int b = 0; b < HBLK; b++) s += nhist[b*NT + tid];
        tot[tid] = s;
    }
    __syncthreads();
    if (tid == 0){ noff[0]=0; for (int t=0;t<NT;t++) noff[t+1]=noff[t]+tot[t]; }
    if (tid < NT){
        int base = 0; for (int t=0;t<tid;t++) base += tot[t];
        int run = 0;
        for (int b=0;b<HBLK;b++){ nbase[b*NT+tid] = base + run; run += nhist[b*NT+tid]; }
    }
    __syncthreads();
    if (tid == 0){
        int c = 0;
        for (int t = 0; t < NT; t++){
            const int ntile = (tot[t] + 31) >> 5;
            for (int rt = 0; rt < ntile; rt++) tlist[c++] = (t << 20) | rt;
        }
        *tcount = c;
    }
}
__global__ __launch_bounds__(256) void k_nscatter(const int* __restrict__ ntype,
    const int* __restrict__ nbase, int* __restrict__ nbucket)
{
    __shared__ int cur[NT];
    const int tid = threadIdx.x, b = blockIdx.x;
    if (tid < NT) cur[tid] = nbase[b*NT + tid];
    __syncthreads();
    const int cn = (NN + HBLK-1)/HBLK;
    const int nEnd = min((b+1)*cn, NN);
    for (int i = b*cn + tid; i < nEnd; i += 256)
        nbucket[atomicAdd(&cur[ntype[i]], 1)] = i;
}

// ---------- edge CSR build: sort by tgt ----------
__global__ void k_zero_bins(int* __restrict__ cnt){
    int i = blockIdx.x*256 + threadIdx.x;
    if (i < NN) cnt[i] = 0;
}
__global__ void k_csr_hist(const int* __restrict__ ei, int* __restrict__ cnt){
    int e = blockIdx.x*256 + threadIdx.x;
    if (e >= NE) return;
    atomicAdd(&cnt[ei[NE+e]], 1);
}
__global__ __launch_bounds__(256) void k_scan1(const int* __restrict__ cnt,
    int* __restrict__ tgt_off, int* __restrict__ bsum)
{
    __shared__ int sh[256];
    const int t = threadIdx.x, b = blockIdx.x;
    const int i = b*256 + t;
    const int v = (i < NN) ? cnt[i] : 0;
    sh[t] = v;
    __syncthreads();
    #pragma unroll
    for (int d = 1; d < 256; d <<= 1){
        const int u = (t >= d) ? sh[t-d] : 0;
        __syncthreads();
        sh[t] += u;
        __syncthreads();
    }
    if (i < NN) tgt_off[i] = sh[t] - v;
    if (t == 255) bsum[b] = sh[255];
}
__global__ __launch_bounds__(128) void k_scan2(const int* __restrict__ bsum,
    int* __restrict__ bbase, int* __restrict__ tgt_off)
{
    __shared__ int sh[128];
    const int t = threadIdx.x;
    const int v = (t < SCB) ? bsum[t] : 0;
    sh[t] = v;
    __syncthreads();
    #pragma unroll
    for (int d = 1; d < 128; d <<= 1){
        const int u = (t >= d) ? sh[t-d] : 0;
        __syncthreads();
        sh[t] += u;
        __syncthreads();
    }
    if (t < SCB) bbase[t] = sh[t] - v;
    if (t == 0) tgt_off[NN] = NE;
}
__global__ __launch_bounds__(256) void k_scan3(int* __restrict__ tgt_off,
    const int* __restrict__ bbase, int* __restrict__ binCur)
{
    const int i = blockIdx.x*256 + threadIdx.x;
    if (i >= NN) return;
    const int o = tgt_off[i] + bbase[blockIdx.x];
    tgt_off[i] = o;
    binCur[i] = o;
}
__global__ void k_csr_scatter(const int* __restrict__ ei, const int* __restrict__ etype,
    const int* __restrict__ etime, const int* __restrict__ ntype,
    int* __restrict__ binCur, int* __restrict__ src_s, int* __restrict__ combo_s,
    int* __restrict__ eid_s)
{
    int e = blockIdx.x*256 + threadIdx.x;
    if (e >= NE) return;
    const int tgt = ei[NE+e], r = etype[e], src = ei[e];
    const int pos = atomicAdd(&binCur[tgt], 1);
    src_s[pos] = src;
    combo_s[pos] = (etime[e]*NT + ntype[src]) | (r << 12);
    eid_s[pos] = e;
}
__global__ void k_tgtmap(const int* __restrict__ tgt_off, int* __restrict__ tgt_srt)
{
    const int n = blockIdx.x*256 + threadIdx.x;
    if (n >= NN) return;
    const int e0 = tgt_off[n], e1 = tgt_off[n+1];
    for (int j = e0; j < e1; j++) tgt_srt[j] = n;
}

// ---------- weight pre-pack (merged): 36 big 256x256 mats -> frag-major f16 ----------
__global__ __launch_bounds__(256) void k_w2f16_big(
    const float* __restrict__ adaptW, const float* __restrict__ qW, const float* __restrict__ kW,
    const float* __restrict__ vW, const float* __restrict__ aW, _Float16* __restrict__ out)
{
    const int y = blockIdx.y;
    const float* src; int m;
    if (y < 4){ src = adaptW; m = y; }
    else if (y < 12){ src = qW; m = y-4; }
    else if (y < 20){ src = kW; m = y-12; }
    else if (y < 28){ src = vW; m = y-20; }
    else { src = aW; m = y-28; }
    const float* ip = src + (size_t)m*65536;
    _Float16* op = out + (size_t)y*65536;
    const int tid4 = blockIdx.x*256 + threadIdx.x;
    const int k4 = tid4 >> 8, c = tid4 & 255;
    f16x4 hv;
    #pragma unroll
    for (int j = 0; j < 4; j++)
        hv[j] = (_Float16)ip[(size_t)(((k4*4 + j) << 8) + c)];
    *reinterpret_cast<f16x4*>(&op[(size_t)tid4 * 4]) = hv;
}
// 256 rel 32x32 mats (att then msg) -> frag-major f16
__global__ __launch_bounds__(256) void k_w2f16_rel(
    const float* __restrict__ attW, const float* __restrict__ msgW, _Float16* __restrict__ out)
{
    const int y = blockIdx.y;
    const float* ip = (y < 128) ? (attW + (size_t)y*1024) : (msgW + (size_t)(y-128)*1024);
    _Float16* op = out + (size_t)y*1024;
    const int tid4 = threadIdx.x;
    const int k4 = tid4 >> 5, c = tid4 & 31;
    f16x4 hv;
    #pragma unroll
    for (int j = 0; j < 4; j++)
        hv[j] = (_Float16)ip[(size_t)(((k4*4 + j) << 5) + c)];
    *reinterpret_cast<f16x4*>(&op[(size_t)tid4 * 4]) = hv;
}

// ---------- act GEMM: out = act(in @ W[t] + b[t]); x stored f16 ----------
__global__ __launch_bounds__(256) void k_x(
    const float* __restrict__ inF, const _Float16* __restrict__ inH,
    const _Float16* __restrict__ Wb, const float* __restrict__ bb, void* __restrict__ out,
    const int* __restrict__ nbucket, const int* __restrict__ noff,
    const int* __restrict__ tlist, const int* __restrict__ tcount,
    int mode, int oh, const float* __restrict__ skipv, const _Float16* __restrict__ xoldH)
{
    if ((int)blockIdx.x >= *tcount) return;
    const int ent = tlist[blockIdx.x];
    const int t = ent >> 20, rowTile = ent & 0xFFFFF;
    const int start = noff[t], cnt = noff[t+1] - start;

    const int tid = threadIdx.x;
    const int w = tid >> 6, lane = tid & 63;
    const int lrow = lane & 15, lgrp = lane >> 4;

    __shared__ _Float16 Al[32][260];
    __shared__ int nid[32];

    if (tid < 32){
        const int gr = rowTile*32 + tid;
        nid[tid] = (gr < cnt) ? nbucket[start + gr] : -1;
    }
    __syncthreads();
    {
        const int r = tid >> 3;
        const int arow = nid[r];
        if (inH){
            const _Float16* ap = (arow >= 0) ? (inH + (size_t)arow*HD) : nullptr;
            #pragma unroll
            for (int j = 0; j < 8; j++){
                const int f4 = (tid & 7) + j*8;
                f16x4 hv = {0,0,0,0};
                if (ap) hv = *reinterpret_cast<const f16x4*>(ap + f4*4);
                *reinterpret_cast<f16x4*>(&Al[r][f4*4]) = hv;
            }
        } else {
            const float* ap = (arow >= 0) ? (inF + (size_t)arow*HD) : nullptr;
            #pragma unroll
            for (int j = 0; j < 8; j++){
                const int f4 = (tid & 7) + j*8;
                float4 v = make_float4(0.f,0.f,0.f,0.f);
                if (ap) v = *reinterpret_cast<const float4*>(ap + f4*4);
                f16x4 hv;
                hv[0]=(_Float16)v.x; hv[1]=(_Float16)v.y; hv[2]=(_Float16)v.z; hv[3]=(_Float16)v.w;
                *reinterpret_cast<f16x4*>(&Al[r][f4*4]) = hv;
            }
        }
    }
    __syncthreads();

    float sk = 0.f;
    if (mode == 2) sk = 1.f/(1.f + __expf(-skipv[t]));

    const _Float16* W = Wb + (size_t)t*HD*HD;
    const float* bias = bb + (size_t)t*HD;
    f32x4v acc[4][2];
    #pragma unroll
    for (int cs = 0; cs < 4; cs++){
        acc[cs][0] = (f32x4v){0.f,0.f,0.f,0.f};
        acc[cs][1] = (f32x4v){0.f,0.f,0.f,0.f};
    }
    #pragma unroll 4
    for (int kc = 0; kc < 16; kc++){
        f16x4 bf[4];
        #pragma unroll
        for (int cs = 0; cs < 4; cs++)
            bf[cs] = *reinterpret_cast<const f16x4*>(
                &W[(size_t)((kc*4 + lgrp)*HD + w*64 + cs*16 + lrow)*4]);
        const f16x4 af0 = *reinterpret_cast<const f16x4*>(&Al[lrow][kc*16 + lgrp*4]);
        const f16x4 af1 = *reinterpret_cast<const f16x4*>(&Al[16 + lrow][kc*16 + lgrp*4]);
        #pragma unroll
        for (int cs = 0; cs < 4; cs++){
            acc[cs][0] = __builtin_amdgcn_mfma_f32_16x16x16f16(af0, bf[cs], acc[cs][0], 0,0,0);
            acc[cs][1] = __builtin_amdgcn_mfma_f32_16x16x16f16(af1, bf[cs], acc[cs][1], 0,0,0);
        }
    }
    #pragma unroll
    for (int cs = 0; cs < 4; cs++){
        const int col = w*64 + cs*16 + lrow;
        const float bcol = bias[col];
        #pragma unroll
        for (int rt = 0; rt < 2; rt++){
            #pragma unroll
            for (int i = 0; i < 4; i++){
                const int lr = rt*16 + lgrp*4 + i;
                const int gr = rowTile*32 + lr;
                if (gr >= cnt) continue;
                const int node = nid[lr];
                float v = acc[cs][rt][i] + bcol;
                if (mode == 1) v = tanhf(v);
                else if (mode == 2){
                    const float xo = (float)xoldH[(size_t)node*HD + col];
                    v = v*sk + xo*(1.f - sk);
                }
                if (oh) ((_Float16*)out)[(size_t)node*HD + col] = (_Float16)v;
                else    ((float*)out)[(size_t)node*HD + col] = v;
            }
        }
    }
}

// ---------- QKV GEMM split by blockIdx.y; LDS-staged coalesced f16x8 output ----------
__global__ __launch_bounds__(256) void k_qkv(
    const _Float16* __restrict__ xh,
    const _Float16* __restrict__ Wq, const float* __restrict__ bq, _Float16* __restrict__ oq,
    const _Float16* __restrict__ Wk, const float* __restrict__ bk, _Float16* __restrict__ okk,
    const _Float16* __restrict__ Wv, const float* __restrict__ bv, _Float16* __restrict__ ov,
    const int* __restrict__ nbucket, const int* __restrict__ noff,
    const int* __restrict__ tlist, const int* __restrict__ tcount)
{
    if ((int)blockIdx.x >= *tcount) return;
    const int ent = tlist[blockIdx.x];
    const int t = ent >> 20, rowTile = ent & 0xFFFFF;
    const int start = noff[t], cnt = noff[t+1] - start;
    const int sel = blockIdx.y;
    const _Float16* Wb = (sel==0 ? Wq : (sel==1 ? Wk : Wv));
    const float* bb = (sel==0 ? bq : (sel==1 ? bk : bv));
    _Float16* out = (sel==0 ? oq : (sel==1 ? okk : ov));

    const int tid = threadIdx.x;
    const int w = tid >> 6, lane = tid & 63;
    const int lrow = lane & 15, lgrp = lane >> 4;

    __shared__ _Float16 Al[32][260];
    __shared__ __align__(16) _Float16 Ol[32][264];
    __shared__ int nid[32];

    if (tid < 32){
        const int gr = rowTile*32 + tid;
        nid[tid] = (gr < cnt) ? nbucket[start + gr] : -1;
    }
    __syncthreads();
    {
        const int r = tid >> 3;
        const int arow = nid[r];
        const _Float16* ap = (arow >= 0) ? (xh + (size_t)arow*HD) : nullptr;
        #pragma unroll
        for (int j = 0; j < 8; j++){
            const int f4 = (tid & 7) + j*8;
            f16x4 hv = {0,0,0,0};
            if (ap) hv = *reinterpret_cast<const f16x4*>(ap + f4*4);
            *reinterpret_cast<f16x4*>(&Al[r][f4*4]) = hv;
        }
    }
    __syncthreads();

    const _Float16* W = Wb + (size_t)t*HD*HD;
    const float* bias = bb + (size_t)t*HD;
    f32x4v acc[4][2];
    #pragma unroll
    for (int cs = 0; cs < 4; cs++){
        acc[cs][0] = (f32x4v){0.f,0.f,0.f,0.f};
        acc[cs][1] = (f32x4v){0.f,0.f,0.f,0.f};
    }
    #pragma unroll 4
    for (int kc = 0; kc < 16; kc++){
        f16x4 bf[4];
        #pragma unroll
        for (int cs = 0; cs < 4; cs++)
            bf[cs] = *reinterpret_cast<const f16x4*>(
                &W[(size_t)((kc*4 + lgrp)*HD + w*64 + cs*16 + lrow)*4]);
        const f16x4 af0 = *reinterpret_cast<const f16x4*>(&Al[lrow][kc*16 + lgrp*4]);
        const f16x4 af1 = *reinterpret_cast<const f16x4*>(&Al[16 + lrow][kc*16 + lgrp*4]);
        #pragma unroll
        for (int cs = 0; cs < 4; cs++){
            acc[cs][0] = __builtin_amdgcn_mfma_f32_16x16x16f16(af0, bf[cs], acc[cs][0], 0,0,0);
            acc[cs][1] = __builtin_amdgcn_mfma_f32_16x16x16f16(af1, bf[cs], acc[cs][1], 0,0,0);
        }
    }
    // stage output tile in LDS (2B writes, conflict-benign), then coalesced flush
    #pragma unroll
    for (int cs = 0; cs < 4; cs++){
        const int col = w*64 + cs*16 + lrow;
        const float bcol = bias[col];
        #pragma unroll
        for (int rt = 0; rt < 2; rt++){
            #pragma unroll
            for (int i = 0; i < 4; i++){
                const int lr = rt*16 + lgrp*4 + i;
                Ol[lr][col] = (_Float16)(acc[cs][rt][i] + bcol);
            }
        }
    }
    __syncthreads();
    {
        const int fcb = tid & 31;           // 16B chunk within row
        #pragma unroll
        for (int it = 0; it < 4; it++){
            const int rr = (tid >> 5) + it*8;
            const int node = nid[rr];
            if (node < 0) continue;
            const f16x8 v = *reinterpret_cast<const f16x8*>(&Ol[rr][fcb*8]);
            *reinterpret_cast<f16x8*>(&out[(size_t)node*HD + fcb*8]) = v;
        }
    }
}

// ---------- small row GEMM: rteP = rte_emb @ rte_W + rte_b (f32 out) ----------
__global__ __launch_bounds__(256) void k_row_gemm(
    const float* __restrict__ A, const float* __restrict__ W, const float* __restrict__ bias,
    float* __restrict__ C)
{
    const int row = blockIdx.x, d = threadIdx.x;
    __shared__ float ar[HD];
    ar[d] = A[(size_t)row*HD + d];
    __syncthreads();
    float acc = bias[d];
    #pragma unroll 8
    for (int k=0;k<HD;k++) acc = fmaf(ar[k], W[(size_t)k*HD + d], acc);
    C[(size_t)row*HD + d] = acc;
}
__global__ __launch_bounds__(256) void k_row_gemm2(
    const float* __restrict__ A, const float* __restrict__ kWb, const float* __restrict__ vWb,
    _Float16* __restrict__ Kc, _Float16* __restrict__ Vc)
{
    const int row = blockIdx.x, ty = blockIdx.y, d = threadIdx.x;
    const float* W = ((blockIdx.z == 0) ? kWb : vWb) + (size_t)ty*HD*HD;
    _Float16* C = (blockIdx.z == 0) ? Kc : Vc;
    __shared__ float ar[HD];
    ar[d] = A[(size_t)row*HD + d];
    __syncthreads();
    float acc = 0.f;
    #pragma unroll 8
    for (int k=0;k<HD;k++) acc = fmaf(ar[k], W[(size_t)k*HD + d], acc);
    C[(size_t)row*(NT*HD) + ty*HD + d] = (_Float16)acc;
}

// ---------- MFMA dual fold (combo tables): grid (nbx, NR, 2) ----------
__global__ __launch_bounds__(256) void k_fold2(
    const _Float16* __restrict__ INa, const _Float16* __restrict__ MATa, _Float16* __restrict__ OUTa,
    const _Float16* __restrict__ INb, const _Float16* __restrict__ MATb, _Float16* __restrict__ OUTb,
    int M, int nbx)
{
    const int r = blockIdx.y;
    const _Float16* IN = blockIdx.z ? INb : INa;
    const _Float16* MATF = blockIdx.z ? MATb : MATa;
    _Float16* OUT = blockIdx.z ? OUTb : OUTa;
    const int lane = threadIdx.x & 63, w = threadIdx.x >> 6;
    const int lrow = lane & 15, lgrp = lane >> 4;
    f16x4 b[NH][2][2];
    const _Float16* Mr = MATF + (size_t)r*NH*1024;
    #pragma unroll
    for (int h = 0; h < NH; h++)
      #pragma unroll
      for (int kb = 0; kb < 2; kb++)
        #pragma unroll
        for (int hf = 0; hf < 2; hf++)
            b[h][kb][hf] = *reinterpret_cast<const f16x4*>(
                &Mr[(size_t)h*1024 + (size_t)(((kb*4 + lgrp)*32) + hf*16 + lrow)*4]);
    const int ntiles = M >> 4;
    for (int t = (int)blockIdx.x*4 + w; t < ntiles; t += nbx*4){
        const int row0 = t*16;
        const _Float16* inrow = IN + (size_t)(row0 + lrow)*HD;
        f16x4 a[NH][2];
        #pragma unroll
        for (int h = 0; h < NH; h++)
          #pragma unroll
          for (int kb = 0; kb < 2; kb++)
              a[h][kb] = *reinterpret_cast<const f16x4*>(&inrow[h*32 + kb*16 + lgrp*4]);
        #pragma unroll
        for (int h = 0; h < NH; h++){
          #pragma unroll
          for (int hf = 0; hf < 2; hf++){
              f32x4v acc = {0.f,0.f,0.f,0.f};
              acc = __builtin_amdgcn_mfma_f32_16x16x16f16(a[h][0], b[h][0][hf], acc, 0,0,0);
              acc = __builtin_amdgcn_mfma_f32_16x16x16f16(a[h][1], b[h][1][hf], acc, 0,0,0);
              #pragma unroll
              for (int i = 0; i < 4; i++){
                  const int rr = lgrp*4 + i;
                  OUT[((size_t)(row0+rr)*NR + r)*HD + h*32 + hf*16 + lrow] = (_Float16)acc[i];
              }
          }
        }
    }
}

// ---------- node fold, XCD-aware, single-pass grid 1024, LDS-transposed stores ----------
// 8 XCDs x 8 tile-ranges x 16 (r,z) items = 1024 blocks = 4 blocks/CU, one dispatch pass.
__global__ __launch_bounds__(256) void k_fold2x(
    const _Float16* __restrict__ INa, const _Float16* __restrict__ MATa, _Float16* __restrict__ OUTa,
    const _Float16* __restrict__ INb, const _Float16* __restrict__ MATb, _Float16* __restrict__ OUTb)
{
    const int bid = blockIdx.x;
    const int xcd = bid & 7;
    const int s = bid >> 3;                 // 0..127
    const int tr = xcd*8 + (s >> 4);        // tile-range 0..63 (all valid)
    const int item = s & 15;
    const int r = item & 7;
    const _Float16* IN = (item >> 3) ? INb : INa;
    const _Float16* MATF = (item >> 3) ? MATb : MATa;
    _Float16* OUT = (item >> 3) ? OUTb : OUTa;

    const int lane = threadIdx.x & 63, w = threadIdx.x >> 6;
    const int lrow = lane & 15, lgrp = lane >> 4;

    __shared__ __align__(16) _Float16 tile[4][16][264];  // per-wave 16x256 (+pad)

    f16x4 b[NH][2][2];
    const _Float16* Mr = MATF + (size_t)r*NH*1024;
    #pragma unroll
    for (int h = 0; h < NH; h++)
      #pragma unroll
      for (int kb = 0; kb < 2; kb++)
        #pragma unroll
        for (int hf = 0; hf < 2; hf++)
            b[h][kb][hf] = *reinterpret_cast<const f16x4*>(
                &Mr[(size_t)h*1024 + (size_t)(((kb*4 + lgrp)*32) + hf*16 + lrow)*4]);

    const int frow = lane >> 5;      // flush: row parity (2 rows per store instr)
    const int fcb  = lane & 31;      // flush: 16B chunk within row
    const int ntiles = NN >> 4;      // 1250
    for (int t = tr*4 + w; t < ntiles; t += FTR*4){
        const int row0 = t*16;
        const _Float16* inrow = IN + (size_t)(row0 + lrow)*HD;
        f16x4 a[NH][2];
        #pragma unroll
        for (int h = 0; h < NH; h++)
          #pragma unroll
          for (int kb = 0; kb < 2; kb++)
              a[h][kb] = *reinterpret_cast<const f16x4*>(&inrow[h*32 + kb*16 + lgrp*4]);
        #pragma unroll
        for (int h = 0; h < NH; h++){
          #pragma unroll
          for (int hf = 0; hf < 2; hf++){
              f32x4v acc = {0.f,0.f,0.f,0.f};
              acc = __builtin_amdgcn_mfma_f32_16x16x16f16(a[h][0], b[h][0][hf], acc, 0,0,0);
              acc = __builtin_amdgcn_mfma_f32_16x16x16f16(a[h][1], b[h][1][hf], acc, 0,0,0);
              const int col = h*32 + hf*16 + lrow;
              #pragma unroll
              for (int i = 0; i < 4; i++)
                  tile[w][lgrp*4 + i][col] = (_Float16)acc[i];
          }
        }
        // intra-wave LDS write->read ordering (per-wave tile; no cross-wave dep)
        asm volatile("s_waitcnt lgkmcnt(0)" ::: "memory");
        __builtin_amdgcn_sched_barrier(0);
        #pragma unroll
        for (int jj = 0; jj < 8; jj++){
            const int rr = jj*2 + frow;
            const f16x8 v = *reinterpret_cast<const f16x8*>(&tile[w][rr][fcb*8]);
            *reinterpret_cast<f16x8*>(&OUT[((size_t)(row0+rr)*NR + r)*HD + fcb*8]) = v;
        }
        asm volatile("s_waitcnt lgkmcnt(0)" ::: "memory");
        __builtin_amdgcn_sched_barrier(0);
    }
}

// ---------- fused edge pass, software-pipelined gathers ----------
__global__ __launch_bounds__(256) void k_edge(
    const _Float16* __restrict__ q0, const _Float16* __restrict__ kA, const _Float16* __restrict__ KcA,
    const _Float16* __restrict__ vM, const _Float16* __restrict__ VcM,
    const float* __restrict__ relP,
    const int* __restrict__ tgt_off, const int* __restrict__ src_s, const int* __restrict__ combo_s,
    _Float16* __restrict__ agg,
    float* __restrict__ s_arr, float* __restrict__ mbuf, float* __restrict__ lbuf, int store_s)
{
    const int n = blockIdx.x*4 + (threadIdx.x >> 6);
    if (n >= NN) return;
    const int lane = threadIdx.x & 63;
    const int h = lane >> 3, c4 = (lane & 7) << 2;
    const int col = h*32 + c4;
    const int e0 = tgt_off[n], e1 = tgt_off[n+1];

    const f16x4 qh = *reinterpret_cast<const f16x4*>(&q0[(size_t)n*HD + col]);
    const float q0v = (float)qh[0], q1v = (float)qh[1], q2v = (float)qh[2], q3v = (float)qh[3];
    float m = -INFINITY, l = 0.f;
    float a0=0.f, a1=0.f, a2=0.f, a3=0.f;

    if (e0 < e1){
        int cwA = combo_s[e0];
        const int srcA0 = src_s[e0];
        const int rA0 = cwA >> 12, comboA0 = cwA & 0xFFF;
        f16x4 kaA = *reinterpret_cast<const f16x4*>(&kA [((size_t)srcA0*NR + rA0)*HD + col]);
        f16x4 kcA = *reinterpret_cast<const f16x4*>(&KcA[((size_t)comboA0*NR + rA0)*HD + col]);
        f16x4 vmA = *reinterpret_cast<const f16x4*>(&vM [((size_t)srcA0*NR + rA0)*HD + col]);
        f16x4 vcA = *reinterpret_cast<const f16x4*>(&VcM[((size_t)comboA0*NR + rA0)*HD + col]);
        const int j1 = min(e0+1, e1-1);
        int srcB = src_s[j1], cwB = combo_s[j1];

        for (int j = e0; j < e1; j++){
            // prefetch rows for j+1 (clamped -> always valid)
            const int rB = cwB >> 12, comboB = cwB & 0xFFF;
            const size_t offSB = ((size_t)srcB*NR + rB)*HD + col;
            const size_t offCB = ((size_t)comboB*NR + rB)*HD + col;
            const f16x4 kaN = *reinterpret_cast<const f16x4*>(&kA [offSB]);
            const f16x4 kcN = *reinterpret_cast<const f16x4*>(&KcA[offCB]);
            const f16x4 vmN = *reinterpret_cast<const f16x4*>(&vM [offSB]);
            const f16x4 vcN = *reinterpret_cast<const f16x4*>(&VcM[offCB]);
            // prefetch indices for j+2 (clamped)
            const int jn = min(j+2, e1-1);
            const int srcN = src_s[jn], cwN = combo_s[jn];

            // compute with current (A) regs
            const int r = cwA >> 12;
            float s = q0v*((float)kaA[0]+(float)kcA[0])
                    + q1v*((float)kaA[1]+(float)kcA[1])
                    + q2v*((float)kaA[2]+(float)kcA[2])
                    + q3v*((float)kaA[3]+(float)kcA[3]);
            s += __shfl_xor(s, 1); s += __shfl_xor(s, 2); s += __shfl_xor(s, 4);
            s *= relP[r*NH + h] * INV_SQRT_DK;
            if (store_s && (lane & 7) == 0) s_arr[(size_t)j*NH + h] = s;
            const float mn = fmaxf(m, s);
            const float sc = __expf(m - mn);     // first edge: m=-inf -> 0
            const float p  = __expf(s - mn);
            l = l*sc + p;
            m = mn;
            a0 = a0*sc + p*((float)vmA[0] + (float)vcA[0]);
            a1 = a1*sc + p*((float)vmA[1] + (float)vcA[1]);
            a2 = a2*sc + p*((float)vmA[2] + (float)vcA[2]);
            a3 = a3*sc + p*((float)vmA[3] + (float)vcA[3]);

            // rotate pipeline
            cwA = cwB;
            kaA = kaN; kcA = kcN; vmA = vmN; vcA = vcN;
            srcB = srcN; cwB = cwN;
        }
    }
    const float inv = (l > 0.f) ? 1.f/l : 0.f;
    a0 *= inv; a1 *= inv; a2 *= inv; a3 *= inv;
    f16x4 o;
    o[0] = (_Float16)(0.5f*a0*(1.f + erff(a0*0.70710678118654752f)));
    o[1] = (_Float16)(0.5f*a1*(1.f + erff(a1*0.70710678118654752f)));
    o[2] = (_Float16)(0.5f*a2*(1.f + erff(a2*0.70710678118654752f)));
    o[3] = (_Float16)(0.5f*a3*(1.f + erff(a3*0.70710678118654752f)));
    *reinterpret_cast<f16x4*>(&agg[(size_t)n*HD + col]) = o;
    if (store_s && (lane & 7) == 0){
        mbuf[(size_t)n*NH + h] = m;
        lbuf[(size_t)n*NH + h] = l;
    }
}

// ---------- alpha output from stored scores (last layer only) ----------
__global__ void k_alpha(const float* __restrict__ s_arr, const int* __restrict__ eid_s,
                        const float* __restrict__ mbuf, const float* __restrict__ lbuf,
                        const int* __restrict__ tgt_srt, float* __restrict__ out_att)
{
    int i = blockIdx.x*256 + threadIdx.x;
    if (i >= NE*NH) return;
    const int j = i >> 3, h = i & 7;
    const int t = tgt_srt[j];
    const float a = __expf(s_arr[i] - mbuf[(size_t)t*NH + h]) / lbuf[(size_t)t*NH + h];
    out_att[(size_t)eid_s[j]*NH + h] = a;
}

extern "C" void kernel_launch(void* const* d_in, const int* in_sizes, int n_in,
                              void* d_out, int out_size, void* d_ws, size_t ws_size,
                              hipStream_t stream)
{
    const float* node_feature = (const float*)d_in[0];
    const int*   node_type    = (const int*)d_in[1];
    const int*   edge_time    = (const int*)d_in[2];
    const int*   edge_index   = (const int*)d_in[3];
    const int*   edge_type    = (const int*)d_in[4];
    const float* adapt_W = (const float*)d_in[5];
    const float* adapt_b = (const float*)d_in[6];
    const float* k_W = (const float*)d_in[7];
    const float* k_b = (const float*)d_in[8];
    const float* q_W = (const float*)d_in[9];
    const float* q_b = (const float*)d_in[10];
    const float* v_W = (const float*)d_in[11];
    const float* v_b = (const float*)d_in[12];
    const float* a_W = (const float*)d_in[13];
    const float* a_b = (const float*)d_in[14];
    const float* rel_pri = (const float*)d_in[15];
    const float* rel_att = (const float*)d_in[16];
    const float* rel_msg = (const float*)d_in[17];
    const float* skip  = (const float*)d_in[18];
    const float* rte_W = (const float*)d_in[19];
    const float* rte_b = (const float*)d_in[20];
    const float* rte_emb = (const float*)d_in[21];

    char* wp = (char*)d_ws;
    auto alloc_f = [&](size_t n)->float*{ float* p=(float*)wp; wp += n*sizeof(float); return p; };
    auto alloc_i = [&](size_t n)->int*  { int*   p=(int*)wp;   wp += n*sizeof(int);   return p; };
    auto alloc_h = [&](size_t n)->_Float16*{ _Float16* p=(_Float16*)wp; wp += n*sizeof(_Float16); return p; };
    _Float16* xh0 = alloc_h((size_t)NN*HD);
    _Float16* xh1 = alloc_h((size_t)NN*HD);
    _Float16* q0h = alloc_h((size_t)NN*HD);
    _Float16* k0h = alloc_h((size_t)NN*HD);
    _Float16* v0h = alloc_h((size_t)NN*HD);
    _Float16* aggh= alloc_h((size_t)NN*HD);
    float* s_arr = alloc_f((size_t)NE*NH);
    float* mbuf  = alloc_f((size_t)NN*NH);
    float* lbuf  = alloc_f((size_t)NN*NH);
    float* rteP  = alloc_f((size_t)MAXL*HD);
    _Float16* Kch = alloc_h((size_t)MAXL*NT*HD);
    _Float16* Vch = alloc_h((size_t)MAXL*NT*HD);
    _Float16* kavm = alloc_h((size_t)NN*NR*HD);            // att node table
    _Float16* vmh  = alloc_h((size_t)NN*NR*HD);            // msg node table
    _Float16* kcaA0 = alloc_h((size_t)MAXL*NT*NR*HD);
    _Float16* kcaA1 = alloc_h((size_t)MAXL*NT*NR*HD);
    _Float16* kcaM0 = alloc_h((size_t)MAXL*NT*NR*HD);
    _Float16* kcaM1 = alloc_h((size_t)MAXL*NT*NR*HD);
    _Float16* wF   = alloc_h((size_t)36*65536);
    _Float16* relF = alloc_h((size_t)256*1024);
    int* nbucket = alloc_i(NN);
    int* nhist   = alloc_i(HBLK*NT);
    int* nbase   = alloc_i(HBLK*NT);
    int* noff    = alloc_i(8);
    int* tlist   = alloc_i(TMAX);
    int* tcount  = alloc_i(8);
    int* cnt     = alloc_i(NN);
    int* bsum    = alloc_i(SCB);
    int* bbase   = alloc_i(SCB);
    int* binCur  = alloc_i(NN);
    int* tgt_off = alloc_i(NN+1);
    int* src_s   = alloc_i(NE);
    int* combo_s = alloc_i(NE);
    int* eid_s   = alloc_i(NE);
    int* tgt_srt = alloc_i(NE);

    const _Float16* adaptF = wF;
    const _Float16* qF = wF + (size_t)4*65536;
    const _Float16* kF = wF + (size_t)12*65536;
    const _Float16* vF = wF + (size_t)20*65536;
    const _Float16* aF = wF + (size_t)28*65536;
    const _Float16* relAF = relF;
    const _Float16* relMF = relF + (size_t)128*1024;

    float* out_att = (float*)d_out;
    float* out_x   = (float*)d_out + (size_t)NE*NH;

    const dim3 gFoldC2(FOLDC, NR, 2);
    const dim3 gQKV(TMAX, 3);
    const int gFoldX = 1024;
    const int gE256 = (NE + 255)/256;
    const int gEH = (NE*NH + 255)/256;
    const int gN256 = (NN + 255)/256;
    const int gEg = (NN + 3)/4;

    // weight pre-pack
    k_w2f16_big<<<dim3(64,36),256,0,stream>>>(adapt_W, q_W, k_W, v_W, a_W, wF);
    k_w2f16_rel<<<dim3(1,256),256,0,stream>>>(rel_att, rel_msg, relF);

    // node buckets + tile list
    k_nhist<<<HBLK,256,0,stream>>>(node_type, nhist);
    k_nscan<<<1,64,0,stream>>>(nhist, noff, nbase, tlist, tcount);
    k_nscatter<<<HBLK,256,0,stream>>>(node_type, nbase, nbucket);

    // edge CSR sorted by tgt
    k_zero_bins<<<SCB,256,0,stream>>>(cnt);
    k_csr_hist<<<gE256,256,0,stream>>>(edge_index, cnt);
    k_scan1<<<SCB,256,0,stream>>>(cnt, tgt_off, bsum);
    k_scan2<<<1,128,0,stream>>>(bsum, bbase, tgt_off);
    k_scan3<<<SCB,256,0,stream>>>(tgt_off, bbase, binCur);
    k_csr_scatter<<<gE256,256,0,stream>>>(edge_index, edge_type, edge_time, node_type,
                                          binCur, src_s, combo_s, eid_s);
    k_tgtmap<<<gN256,256,0,stream>>>(tgt_off, tgt_srt);

    // preamble: layer-invariant combo tables (merged att+msg folds)
    {
        k_row_gemm<<<MAXL,256,0,stream>>>(rte_emb, rte_W, rte_b, rteP);
        k_row_gemm2<<<dim3(MAXL,NT,2),256,0,stream>>>(rteP, k_W, v_W, Kch, Vch);
        k_fold2<<<gFoldC2,256,0,stream>>>(Kch, relAF, kcaA0, Vch, relMF, kcaM0, MAXL*NT, FOLDC);
        k_row_gemm<<<MAXL,256,0,stream>>>(rte_emb, rte_W + (size_t)HD*HD, rte_b + HD, rteP);
        k_row_gemm2<<<dim3(MAXL,NT,2),256,0,stream>>>(rteP, k_W + (size_t)NT*HD*HD,
                                                      v_W + (size_t)NT*HD*HD, Kch, Vch);
        k_fold2<<<gFoldC2,256,0,stream>>>(Kch, relAF + (size_t)NR*NH*1024, kcaA1,
                                          Vch, relMF + (size_t)NR*NH*1024, kcaM1, MAXL*NT, FOLDC);
    }

    // adapt -> xh0 (f16), then split QKV(l=0)
    k_x<<<TMAX,256,0,stream>>>(node_feature, nullptr, adaptF, adapt_b, xh0,
                               nbucket, noff, tlist, tcount, 1, 1, nullptr, nullptr);
    k_qkv<<<gQKV,256,0,stream>>>(xh0, qF, q_b, q0h, kF, k_b, k0h, vF, v_b, v0h,
                                 nbucket, noff, tlist, tcount);

    for (int l = 0; l < NL; l++){
        const _Float16* rAF = relAF + (size_t)l*NR*NH*1024;
        const _Float16* rMF = relMF + (size_t)l*NR*NH*1024;
        const _Float16* kcaA = (l == 0) ? kcaA0 : kcaA1;
        const _Float16* kcaM = (l == 0) ? kcaM0 : kcaM1;
        const int store_s = (l == NL-1) ? 1 : 0;
        // merged node folds (att + msg), XCD-aware single-pass grid + coalesced stores
        k_fold2x<<<gFoldX,256,0,stream>>>(k0h, rAF, kavm, v0h, rMF, vmh);
        // fused score + online softmax + aggregate + gelu (pipelined gathers)
        k_edge<<<gEg,256,0,stream>>>(q0h, kavm, kcaA, vmh, kcaM,
                                     rel_pri + (size_t)l*NR*NH,
                                     tgt_off, src_s, combo_s, aggh,
                                     s_arr, mbuf, lbuf, store_s);
        if (store_s)
            k_alpha<<<gEH,256,0,stream>>>(s_arr, eid_s, mbuf, lbuf, tgt_srt, out_att);
        // aW(l); next-layer x + QKV if not last
        if (l == 0){
            k_x<<<TMAX,256,0,stream>>>(nullptr, aggh, aF, a_b, xh1,
                                       nbucket, noff, tlist, tcount, 2, 1, skip, xh0);
            k_qkv<<<gQKV,256,0,stream>>>(xh1, qF + (size_t)NT*HD*HD, q_b + (size_t)NT*HD, q0h,
                                         kF + (size_t)NT*HD*HD, k_b + (size_t)NT*HD, k0h,
                                         vF + (size_t)NT*HD*HD, v_b + (size_t)NT*HD, v0h,
                                         nbucket, noff, tlist, tcount);
        } else {
            k_x<<<TMAX,256,0,stream>>>(nullptr, aggh, aF + (size_t)NT*HD*HD, a_b + (size_t)NT*HD,
                                       out_x, nbucket, noff, tlist, tcount, 2, 0, skip + NT, xh1);
        }
    }
}

// Round 33
// 484.733 us; speedup vs baseline: 1.0187x; 1.0058x over previous
//
#include <hip/hip_runtime.h>
#include <hip/hip_fp16.h>

#define NN    20000
#define NE    150000
#define HD    256
#define NT    4
#define NR    8
#define NH    8
#define DKq   32
#define NL    2
#define MAXL  240
#define HBLK  256
#define SCB   ((NN + 255)/256)
#define TMAX  632
#define FOLDC 15
#define FTR   64              /* node-fold tile-ranges: 8 XCD x 8 */
#define INV_SQRT_DK 0.17677669529663687f

typedef _Float16 f16x4 __attribute__((ext_vector_type(4)));
typedef _Float16 f16x8 __attribute__((ext_vector_type(8)));
typedef float    f32x4v __attribute__((ext_vector_type(4)));

// ---------- node bucketing (by type) + compact 32-row tile list ----------
__global__ __launch_bounds__(256) void k_nhist(const int* __restrict__ ntype, int* __restrict__ nhist)
{
    __shared__ int h[NT];
    const int tid = threadIdx.x, b = blockIdx.x;
    if (tid < NT) h[tid] = 0;
    __syncthreads();
    const int cn = (NN + HBLK-1)/HBLK;
    const int nEnd = min((b+1)*cn, NN);
    for (int i = b*cn + tid; i < nEnd; i += 256) atomicAdd(&h[ntype[i]], 1);
    __syncthreads();
    if (tid < NT) nhist[b*NT + tid] = h[tid];
}
__global__ void k_nscan(const int* __restrict__ nhist, int* __restrict__ noff, int* __restrict__ nbase,
                        int* __restrict__ tlist, int* __restrict__ tcount)
{
    __shared__ int tot[NT];
    const int tid = threadIdx.x;
    if (tid < NT){
        int s = 0;
        for (int b = 0; b < HBLK; b++) s += nhist[b*NT + tid];
        tot[tid] = s;
    }
    __syncthreads();
    if (tid == 0){ noff[0]=0; for (int t=0;t<NT;t++) noff[t+1]=noff[t]+tot[t]; }
    if (tid < NT){
        int base = 0; for (int t=0;t<tid;t++) base += tot[t];
        int run = 0;
        for (int b=0;b<HBLK;b++){ nbase[b*NT+tid] = base + run; run += nhist[b*NT+tid]; }
    }
    __syncthreads();
    if (tid == 0){
        int c = 0;
        for (int t = 0; t < NT; t++){
            const int ntile = (tot[t] + 31) >> 5;
            for (int rt = 0; rt < ntile; rt++) tlist[c++] = (t << 20) | rt;
        }
        *tcount = c;
    }
}
__global__ __launch_bounds__(256) void k_nscatter(const int* __restrict__ ntype,
    const int* __restrict__ nbase, int* __restrict__ nbucket)
{
    __shared__ int cur[NT];
    const int tid = threadIdx.x, b = blockIdx.x;
    if (tid < NT) cur[tid] = nbase[b*NT + tid];
    __syncthreads();
    const int cn = (NN + HBLK-1)/HBLK;
    const int nEnd = min((b+1)*cn, NN);
    for (int i = b*cn + tid; i < nEnd; i += 256)
        nbucket[atomicAdd(&cur[ntype[i]], 1)] = i;
}

// ---------- edge CSR build: sort by tgt ----------
__global__ void k_zero_bins(int* __restrict__ cnt){
    int i = blockIdx.x*256 + threadIdx.x;
    if (i < NN) cnt[i] = 0;
}
__global__ void k_csr_hist(const int* __restrict__ ei, int* __restrict__ cnt){
    int e = blockIdx.x*256 + threadIdx.x;
    if (e >= NE) return;
    atomicAdd(&cnt[ei[NE+e]], 1);
}
__global__ __launch_bounds__(256) void k_scan1(const int* __restrict__ cnt,
    int* __restrict__ tgt_off, int* __restrict__ bsum)
{
    __shared__ int sh[256];
    const int t = threadIdx.x, b = blockIdx.x;
    const int i = b*256 + t;
    const int v = (i < NN) ? cnt[i] : 0;
    sh[t] = v;
    __syncthreads();
    #pragma unroll
    for (int d = 1; d < 256; d <<= 1){
        const int u = (t >= d) ? sh[t-d] : 0;
        __syncthreads();
        sh[t] += u;
        __syncthreads();
    }
    if (i < NN) tgt_off[i] = sh[t] - v;
    if (t == 255) bsum[b] = sh[255];
}
__global__ __launch_bounds__(128) void k_scan2(const int* __restrict__ bsum,
    int* __restrict__ bbase, int* __restrict__ tgt_off)
{
    __shared__ int sh[128];
    const int t = threadIdx.x;
    const int v = (t < SCB) ? bsum[t] : 0;
    sh[t] = v;
    __syncthreads();
    #pragma unroll
    for (int d = 1; d < 128; d <<= 1){
        const int u = (t >= d) ? sh[t-d] : 0;
        __syncthreads();
        sh[t] += u;
        __syncthreads();
    }
    if (t < SCB) bbase[t] = sh[t] - v;
    if (t == 0) tgt_off[NN] = NE;
}
__global__ __launch_bounds__(256) void k_scan3(int* __restrict__ tgt_off,
    const int* __restrict__ bbase, int* __restrict__ binCur)
{
    const int i = blockIdx.x*256 + threadIdx.x;
    if (i >= NN) return;
    const int o = tgt_off[i] + bbase[blockIdx.x];
    tgt_off[i] = o;
    binCur[i] = o;
}
__global__ void k_csr_scatter(const int* __restrict__ ei, const int* __restrict__ etype,
    const int* __restrict__ etime, const int* __restrict__ ntype,
    int* __restrict__ binCur, int* __restrict__ src_s, int* __restrict__ combo_s,
    int* __restrict__ eid_s)
{
    int e = blockIdx.x*256 + threadIdx.x;
    if (e >= NE) return;
    const int tgt = ei[NE+e], r = etype[e], src = ei[e];
    const int pos = atomicAdd(&binCur[tgt], 1);
    src_s[pos] = src;
    combo_s[pos] = (etime[e]*NT + ntype[src]) | (r << 12);
    eid_s[pos] = e;
}
__global__ void k_tgtmap(const int* __restrict__ tgt_off, int* __restrict__ tgt_srt)
{
    const int n = blockIdx.x*256 + threadIdx.x;
    if (n >= NN) return;
    const int e0 = tgt_off[n], e1 = tgt_off[n+1];
    for (int j = e0; j < e1; j++) tgt_srt[j] = n;
}

// ---------- weight pre-pack (merged): 36 big 256x256 mats -> frag-major f16 ----------
__global__ __launch_bounds__(256) void k_w2f16_big(
    const float* __restrict__ adaptW, const float* __restrict__ qW, const float* __restrict__ kW,
    const float* __restrict__ vW, const float* __restrict__ aW, _Float16* __restrict__ out)
{
    const int y = blockIdx.y;
    const float* src; int m;
    if (y < 4){ src = adaptW; m = y; }
    else if (y < 12){ src = qW; m = y-4; }
    else if (y < 20){ src = kW; m = y-12; }
    else if (y < 28){ src = vW; m = y-20; }
    else { src = aW; m = y-28; }
    const float* ip = src + (size_t)m*65536;
    _Float16* op = out + (size_t)y*65536;
    const int tid4 = blockIdx.x*256 + threadIdx.x;
    const int k4 = tid4 >> 8, c = tid4 & 255;
    f16x4 hv;
    #pragma unroll
    for (int j = 0; j < 4; j++)
        hv[j] = (_Float16)ip[(size_t)(((k4*4 + j) << 8) + c)];
    *reinterpret_cast<f16x4*>(&op[(size_t)tid4 * 4]) = hv;
}
// 256 rel 32x32 mats -> frag-major f16.
// att half (y<128) packed TRANSPOSED: B[k][d] = M[d][k], for q-side folding
// (qr[d] = sum_k q[k] M[d][k]).  msg half packed as stored (k-side fold).
__global__ __launch_bounds__(256) void k_w2f16_rel(
    const float* __restrict__ attW, const float* __restrict__ msgW, _Float16* __restrict__ out)
{
    const int y = blockIdx.y;
    const float* ip = (y < 128) ? (attW + (size_t)y*1024) : (msgW + (size_t)(y-128)*1024);
    _Float16* op = out + (size_t)y*1024;
    const int tid4 = threadIdx.x;
    const int k4 = tid4 >> 5, c = tid4 & 31;
    f16x4 hv;
    if (y < 128){
        #pragma unroll
        for (int j = 0; j < 4; j++)
            hv[j] = (_Float16)ip[(size_t)((c << 5) + (k4*4 + j))];       // transposed
    } else {
        #pragma unroll
        for (int j = 0; j < 4; j++)
            hv[j] = (_Float16)ip[(size_t)(((k4*4 + j) << 5) + c)];
    }
    *reinterpret_cast<f16x4*>(&op[(size_t)tid4 * 4]) = hv;
}

// ---------- act GEMM: out = act(in @ W[t] + b[t]); x stored f16 ----------
__global__ __launch_bounds__(256) void k_x(
    const float* __restrict__ inF, const _Float16* __restrict__ inH,
    const _Float16* __restrict__ Wb, const float* __restrict__ bb, void* __restrict__ out,
    const int* __restrict__ nbucket, const int* __restrict__ noff,
    const int* __restrict__ tlist, const int* __restrict__ tcount,
    int mode, int oh, const float* __restrict__ skipv, const _Float16* __restrict__ xoldH)
{
    if ((int)blockIdx.x >= *tcount) return;
    const int ent = tlist[blockIdx.x];
    const int t = ent >> 20, rowTile = ent & 0xFFFFF;
    const int start = noff[t], cnt = noff[t+1] - start;

    const int tid = threadIdx.x;
    const int w = tid >> 6, lane = tid & 63;
    const int lrow = lane & 15, lgrp = lane >> 4;

    __shared__ _Float16 Al[32][260];
    __shared__ int nid[32];

    if (tid < 32){
        const int gr = rowTile*32 + tid;
        nid[tid] = (gr < cnt) ? nbucket[start + gr] : -1;
    }
    __syncthreads();
    {
        const int r = tid >> 3;
        const int arow = nid[r];
        if (inH){
            const _Float16* ap = (arow >= 0) ? (inH + (size_t)arow*HD) : nullptr;
            #pragma unroll
            for (int j = 0; j < 8; j++){
                const int f4 = (tid & 7) + j*8;
                f16x4 hv = {0,0,0,0};
                if (ap) hv = *reinterpret_cast<const f16x4*>(ap + f4*4);
                *reinterpret_cast<f16x4*>(&Al[r][f4*4]) = hv;
            }
        } else {
            const float* ap = (arow >= 0) ? (inF + (size_t)arow*HD) : nullptr;
            #pragma unroll
            for (int j = 0; j < 8; j++){
                const int f4 = (tid & 7) + j*8;
                float4 v = make_float4(0.f,0.f,0.f,0.f);
                if (ap) v = *reinterpret_cast<const float4*>(ap + f4*4);
                f16x4 hv;
                hv[0]=(_Float16)v.x; hv[1]=(_Float16)v.y; hv[2]=(_Float16)v.z; hv[3]=(_Float16)v.w;
                *reinterpret_cast<f16x4*>(&Al[r][f4*4]) = hv;
            }
        }
    }
    __syncthreads();

    float sk = 0.f;
    if (mode == 2) sk = 1.f/(1.f + __expf(-skipv[t]));

    const _Float16* W = Wb + (size_t)t*HD*HD;
    const float* bias = bb + (size_t)t*HD;
    f32x4v acc[4][2];
    #pragma unroll
    for (int cs = 0; cs < 4; cs++){
        acc[cs][0] = (f32x4v){0.f,0.f,0.f,0.f};
        acc[cs][1] = (f32x4v){0.f,0.f,0.f,0.f};
    }
    #pragma unroll 4
    for (int kc = 0; kc < 16; kc++){
        f16x4 bf[4];
        #pragma unroll
        for (int cs = 0; cs < 4; cs++)
            bf[cs] = *reinterpret_cast<const f16x4*>(
                &W[(size_t)((kc*4 + lgrp)*HD + w*64 + cs*16 + lrow)*4]);
        const f16x4 af0 = *reinterpret_cast<const f16x4*>(&Al[lrow][kc*16 + lgrp*4]);
        const f16x4 af1 = *reinterpret_cast<const f16x4*>(&Al[16 + lrow][kc*16 + lgrp*4]);
        #pragma unroll
        for (int cs = 0; cs < 4; cs++){
            acc[cs][0] = __builtin_amdgcn_mfma_f32_16x16x16f16(af0, bf[cs], acc[cs][0], 0,0,0);
            acc[cs][1] = __builtin_amdgcn_mfma_f32_16x16x16f16(af1, bf[cs], acc[cs][1], 0,0,0);
        }
    }
    #pragma unroll
    for (int cs = 0; cs < 4; cs++){
        const int col = w*64 + cs*16 + lrow;
        const float bcol = bias[col];
        #pragma unroll
        for (int rt = 0; rt < 2; rt++){
            #pragma unroll
            for (int i = 0; i < 4; i++){
                const int lr = rt*16 + lgrp*4 + i;
                const int gr = rowTile*32 + lr;
                if (gr >= cnt) continue;
                const int node = nid[lr];
                float v = acc[cs][rt][i] + bcol;
                if (mode == 1) v = tanhf(v);
                else if (mode == 2){
                    const float xo = (float)xoldH[(size_t)node*HD + col];
                    v = v*sk + xo*(1.f - sk);
                }
                if (oh) ((_Float16*)out)[(size_t)node*HD + col] = (_Float16)v;
                else    ((float*)out)[(size_t)node*HD + col] = v;
            }
        }
    }
}

// ---------- QKV GEMM split by blockIdx.y; LDS-staged coalesced f16x8 output ----------
__global__ __launch_bounds__(256) void k_qkv(
    const _Float16* __restrict__ xh,
    const _Float16* __restrict__ Wq, const float* __restrict__ bq, _Float16* __restrict__ oq,
    const _Float16* __restrict__ Wk, const float* __restrict__ bk, _Float16* __restrict__ okk,
    const _Float16* __restrict__ Wv, const float* __restrict__ bv, _Float16* __restrict__ ov,
    const int* __restrict__ nbucket, const int* __restrict__ noff,
    const int* __restrict__ tlist, const int* __restrict__ tcount)
{
    if ((int)blockIdx.x >= *tcount) return;
    const int ent = tlist[blockIdx.x];
    const int t = ent >> 20, rowTile = ent & 0xFFFFF;
    const int start = noff[t], cnt = noff[t+1] - start;
    const int sel = blockIdx.y;
    const _Float16* Wb = (sel==0 ? Wq : (sel==1 ? Wk : Wv));
    const float* bb = (sel==0 ? bq : (sel==1 ? bk : bv));
    _Float16* out = (sel==0 ? oq : (sel==1 ? okk : ov));

    const int tid = threadIdx.x;
    const int w = tid >> 6, lane = tid & 63;
    const int lrow = lane & 15, lgrp = lane >> 4;

    __shared__ _Float16 Al[32][260];
    __shared__ __align__(16) _Float16 Ol[32][264];
    __shared__ int nid[32];

    if (tid < 32){
        const int gr = rowTile*32 + tid;
        nid[tid] = (gr < cnt) ? nbucket[start + gr] : -1;
    }
    __syncthreads();
    {
        const int r = tid >> 3;
        const int arow = nid[r];
        const _Float16* ap = (arow >= 0) ? (xh + (size_t)arow*HD) : nullptr;
        #pragma unroll
        for (int j = 0; j < 8; j++){
            const int f4 = (tid & 7) + j*8;
            f16x4 hv = {0,0,0,0};
            if (ap) hv = *reinterpret_cast<const f16x4*>(ap + f4*4);
            *reinterpret_cast<f16x4*>(&Al[r][f4*4]) = hv;
        }
    }
    __syncthreads();

    const _Float16* W = Wb + (size_t)t*HD*HD;
    const float* bias = bb + (size_t)t*HD;
    f32x4v acc[4][2];
    #pragma unroll
    for (int cs = 0; cs < 4; cs++){
        acc[cs][0] = (f32x4v){0.f,0.f,0.f,0.f};
        acc[cs][1] = (f32x4v){0.f,0.f,0.f,0.f};
    }
    #pragma unroll 4
    for (int kc = 0; kc < 16; kc++){
        f16x4 bf[4];
        #pragma unroll
        for (int cs = 0; cs < 4; cs++)
            bf[cs] = *reinterpret_cast<const f16x4*>(
                &W[(size_t)((kc*4 + lgrp)*HD + w*64 + cs*16 + lrow)*4]);
        const f16x4 af0 = *reinterpret_cast<const f16x4*>(&Al[lrow][kc*16 + lgrp*4]);
        const f16x4 af1 = *reinterpret_cast<const f16x4*>(&Al[16 + lrow][kc*16 + lgrp*4]);
        #pragma unroll
        for (int cs = 0; cs < 4; cs++){
            acc[cs][0] = __builtin_amdgcn_mfma_f32_16x16x16f16(af0, bf[cs], acc[cs][0], 0,0,0);
            acc[cs][1] = __builtin_amdgcn_mfma_f32_16x16x16f16(af1, bf[cs], acc[cs][1], 0,0,0);
        }
    }
    // stage output tile in LDS (2B writes, conflict-benign), then coalesced flush
    #pragma unroll
    for (int cs = 0; cs < 4; cs++){
        const int col = w*64 + cs*16 + lrow;
        const float bcol = bias[col];
        #pragma unroll
        for (int rt = 0; rt < 2; rt++){
            #pragma unroll
            for (int i = 0; i < 4; i++){
                const int lr = rt*16 + lgrp*4 + i;
                Ol[lr][col] = (_Float16)(acc[cs][rt][i] + bcol);
            }
        }
    }
    __syncthreads();
    {
        const int fcb = tid & 31;           // 16B chunk within row
        #pragma unroll
        for (int it = 0; it < 4; it++){
            const int rr = (tid >> 5) + it*8;
            const int node = nid[rr];
            if (node < 0) continue;
            const f16x8 v = *reinterpret_cast<const f16x8*>(&Ol[rr][fcb*8]);
            *reinterpret_cast<f16x8*>(&out[(size_t)node*HD + fcb*8]) = v;
        }
    }
}

// ---------- small row GEMM: rteP = rte_emb @ rte_W + rte_b (f32 out) ----------
__global__ __launch_bounds__(256) void k_row_gemm(
    const float* __restrict__ A, const float* __restrict__ W, const float* __restrict__ bias,
    float* __restrict__ C)
{
    const int row = blockIdx.x, d = threadIdx.x;
    __shared__ float ar[HD];
    ar[d] = A[(size_t)row*HD + d];
    __syncthreads();
    float acc = bias[d];
    #pragma unroll 8
    for (int k=0;k<HD;k++) acc = fmaf(ar[k], W[(size_t)k*HD + d], acc);
    C[(size_t)row*HD + d] = acc;
}
__global__ __launch_bounds__(256) void k_row_gemm2(
    const float* __restrict__ A, const float* __restrict__ kWb, const float* __restrict__ vWb,
    _Float16* __restrict__ Kc, _Float16* __restrict__ Vc)
{
    const int row = blockIdx.x, ty = blockIdx.y, d = threadIdx.x;
    const float* W = ((blockIdx.z == 0) ? kWb : vWb) + (size_t)ty*HD*HD;
    _Float16* C = (blockIdx.z == 0) ? Kc : Vc;
    __shared__ float ar[HD];
    ar[d] = A[(size_t)row*HD + d];
    __syncthreads();
    float acc = 0.f;
    #pragma unroll 8
    for (int k=0;k<HD;k++) acc = fmaf(ar[k], W[(size_t)k*HD + d], acc);
    C[(size_t)row*(NT*HD) + ty*HD + d] = (_Float16)acc;
}

// ---------- MFMA fold (combo msg table): grid (nbx, NR) ----------
__global__ __launch_bounds__(256) void k_fold2(
    const _Float16* __restrict__ IN, const _Float16* __restrict__ MATF, _Float16* __restrict__ OUT,
    int M, int nbx)
{
    const int r = blockIdx.y;
    const int lane = threadIdx.x & 63, w = threadIdx.x >> 6;
    const int lrow = lane & 15, lgrp = lane >> 4;
    f16x4 b[NH][2][2];
    const _Float16* Mr = MATF + (size_t)r*NH*1024;
    #pragma unroll
    for (int h = 0; h < NH; h++)
      #pragma unroll
      for (int kb = 0; kb < 2; kb++)
        #pragma unroll
        for (int hf = 0; hf < 2; hf++)
            b[h][kb][hf] = *reinterpret_cast<const f16x4*>(
                &Mr[(size_t)h*1024 + (size_t)(((kb*4 + lgrp)*32) + hf*16 + lrow)*4]);
    const int ntiles = M >> 4;
    for (int t = (int)blockIdx.x*4 + w; t < ntiles; t += nbx*4){
        const int row0 = t*16;
        const _Float16* inrow = IN + (size_t)(row0 + lrow)*HD;
        f16x4 a[NH][2];
        #pragma unroll
        for (int h = 0; h < NH; h++)
          #pragma unroll
          for (int kb = 0; kb < 2; kb++)
              a[h][kb] = *reinterpret_cast<const f16x4*>(&inrow[h*32 + kb*16 + lgrp*4]);
        #pragma unroll
        for (int h = 0; h < NH; h++){
          #pragma unroll
          for (int hf = 0; hf < 2; hf++){
              f32x4v acc = {0.f,0.f,0.f,0.f};
              acc = __builtin_amdgcn_mfma_f32_16x16x16f16(a[h][0], b[h][0][hf], acc, 0,0,0);
              acc = __builtin_amdgcn_mfma_f32_16x16x16f16(a[h][1], b[h][1][hf], acc, 0,0,0);
              #pragma unroll
              for (int i = 0; i < 4; i++){
                  const int rr = lgrp*4 + i;
                  OUT[((size_t)(row0+rr)*NR + r)*HD + h*32 + hf*16 + lrow] = (_Float16)acc[i];
              }
          }
        }
    }
}

// ---------- node fold, XCD-aware, single-pass grid 1024, LDS-transposed stores ----------
// z=0: q0h @ relA^T -> qfold ; z=1: v0h @ relM -> vmh
__global__ __launch_bounds__(256) void k_fold2x(
    const _Float16* __restrict__ INa, const _Float16* __restrict__ MATa, _Float16* __restrict__ OUTa,
    const _Float16* __restrict__ INb, const _Float16* __restrict__ MATb, _Float16* __restrict__ OUTb)
{
    const int bid = blockIdx.x;
    const int xcd = bid & 7;
    const int s = bid >> 3;                 // 0..127
    const int tr = xcd*8 + (s >> 4);        // tile-range 0..63 (all valid)
    const int item = s & 15;
    const int r = item & 7;
    const _Float16* IN = (item >> 3) ? INb : INa;
    const _Float16* MATF = (item >> 3) ? MATb : MATa;
    _Float16* OUT = (item >> 3) ? OUTb : OUTa;

    const int lane = threadIdx.x & 63, w = threadIdx.x >> 6;
    const int lrow = lane & 15, lgrp = lane >> 4;

    __shared__ __align__(16) _Float16 tile[4][16][264];  // per-wave 16x256 (+pad)

    f16x4 b[NH][2][2];
    const _Float16* Mr = MATF + (size_t)r*NH*1024;
    #pragma unroll
    for (int h = 0; h < NH; h++)
      #pragma unroll
      for (int kb = 0; kb < 2; kb++)
        #pragma unroll
        for (int hf = 0; hf < 2; hf++)
            b[h][kb][hf] = *reinterpret_cast<const f16x4*>(
                &Mr[(size_t)h*1024 + (size_t)(((kb*4 + lgrp)*32) + hf*16 + lrow)*4]);

    const int frow = lane >> 5;      // flush: row parity (2 rows per store instr)
    const int fcb  = lane & 31;      // flush: 16B chunk within row
    const int ntiles = NN >> 4;      // 1250
    for (int t = tr*4 + w; t < ntiles; t += FTR*4){
        const int row0 = t*16;
        const _Float16* inrow = IN + (size_t)(row0 + lrow)*HD;
        f16x4 a[NH][2];
        #pragma unroll
        for (int h = 0; h < NH; h++)
          #pragma unroll
          for (int kb = 0; kb < 2; kb++)
              a[h][kb] = *reinterpret_cast<const f16x4*>(&inrow[h*32 + kb*16 + lgrp*4]);
        #pragma unroll
        for (int h = 0; h < NH; h++){
          #pragma unroll
          for (int hf = 0; hf < 2; hf++){
              f32x4v acc = {0.f,0.f,0.f,0.f};
              acc = __builtin_amdgcn_mfma_f32_16x16x16f16(a[h][0], b[h][0][hf], acc, 0,0,0);
              acc = __builtin_amdgcn_mfma_f32_16x16x16f16(a[h][1], b[h][1][hf], acc, 0,0,0);
              const int col = h*32 + hf*16 + lrow;
              #pragma unroll
              for (int i = 0; i < 4; i++)
                  tile[w][lgrp*4 + i][col] = (_Float16)acc[i];
          }
        }
        // intra-wave LDS write->read ordering (per-wave tile; no cross-wave dep)
        asm volatile("s_waitcnt lgkmcnt(0)" ::: "memory");
        __builtin_amdgcn_sched_barrier(0);
        #pragma unroll
        for (int jj = 0; jj < 8; jj++){
            const int rr = jj*2 + frow;
            const f16x8 v = *reinterpret_cast<const f16x8*>(&tile[w][rr][fcb*8]);
            *reinterpret_cast<f16x8*>(&OUT[((size_t)(row0+rr)*NR + r)*HD + fcb*8]) = v;
        }
        asm volatile("s_waitcnt lgkmcnt(0)" ::: "memory");
        __builtin_amdgcn_sched_barrier(0);
    }
}

// ---------- fused edge pass, q-side folded score, software-pipelined gathers ----------
// s = qfold[n][r] . (k0h[src] + Kch[combo]);  msg = vmh[src][r] + kcaM[combo][r]
__global__ __launch_bounds__(256) void k_edge(
    const _Float16* __restrict__ qF, const _Float16* __restrict__ k0,
    const _Float16* __restrict__ KcT,
    const _Float16* __restrict__ vM, const _Float16* __restrict__ VcM,
    const float* __restrict__ relP,
    const int* __restrict__ tgt_off, const int* __restrict__ src_s, const int* __restrict__ combo_s,
    _Float16* __restrict__ agg,
    float* __restrict__ s_arr, float* __restrict__ mbuf, float* __restrict__ lbuf, int store_s)
{
    const int n = blockIdx.x*4 + (threadIdx.x >> 6);
    if (n >= NN) return;
    const int lane = threadIdx.x & 63;
    const int h = lane >> 3, c4 = (lane & 7) << 2;
    const int col = h*32 + c4;
    const int e0 = tgt_off[n], e1 = tgt_off[n+1];

    float m = -INFINITY, l = 0.f;
    float a0=0.f, a1=0.f, a2=0.f, a3=0.f;

    if (e0 < e1){
        int cwA = combo_s[e0];
        const int srcA0 = src_s[e0];
        const int rA0 = cwA >> 12, comboA0 = cwA & 0xFFF;
        f16x4 qfA = *reinterpret_cast<const f16x4*>(&qF [((size_t)n*NR + rA0)*HD + col]);
        f16x4 kkA = *reinterpret_cast<const f16x4*>(&k0 [(size_t)srcA0*HD + col]);
        f16x4 kcA = *reinterpret_cast<const f16x4*>(&KcT[(size_t)comboA0*HD + col]);
        f16x4 vmA = *reinterpret_cast<const f16x4*>(&vM [((size_t)srcA0*NR + rA0)*HD + col]);
        f16x4 vcA = *reinterpret_cast<const f16x4*>(&VcM[((size_t)comboA0*NR + rA0)*HD + col]);
        const int j1 = min(e0+1, e1-1);
        int srcB = src_s[j1], cwB = combo_s[j1];

        for (int j = e0; j < e1; j++){
            // prefetch rows for j+1 (clamped -> always valid)
            const int rB = cwB >> 12, comboB = cwB & 0xFFF;
            const f16x4 qfN = *reinterpret_cast<const f16x4*>(&qF [((size_t)n*NR + rB)*HD + col]);
            const f16x4 kkN = *reinterpret_cast<const f16x4*>(&k0 [(size_t)srcB*HD + col]);
            const f16x4 kcN = *reinterpret_cast<const f16x4*>(&KcT[(size_t)comboB*HD + col]);
            const f16x4 vmN = *reinterpret_cast<const f16x4*>(&vM [((size_t)srcB*NR + rB)*HD + col]);
            const f16x4 vcN = *reinterpret_cast<const f16x4*>(&VcM[((size_t)comboB*NR + rB)*HD + col]);
            // prefetch indices for j+2 (clamped)
            const int jn = min(j+2, e1-1);
            const int srcN = src_s[jn], cwN = combo_s[jn];

            // compute with current (A) regs
            const int r = cwA >> 12;
            float s = (float)qfA[0]*((float)kkA[0]+(float)kcA[0])
                    + (float)qfA[1]*((float)kkA[1]+(float)kcA[1])
                    + (float)qfA[2]*((float)kkA[2]+(float)kcA[2])
                    + (float)qfA[3]*((float)kkA[3]+(float)kcA[3]);
            s += __shfl_xor(s, 1); s += __shfl_xor(s, 2); s += __shfl_xor(s, 4);
            s *= relP[r*NH + h] * INV_SQRT_DK;
            if (store_s && (lane & 7) == 0) s_arr[(size_t)j*NH + h] = s;
            const float mn = fmaxf(m, s);
            const float sc = __expf(m - mn);     // first edge: m=-inf -> 0
            const float p  = __expf(s - mn);
            l = l*sc + p;
            m = mn;
            a0 = a0*sc + p*((float)vmA[0] + (float)vcA[0]);
            a1 = a1*sc + p*((float)vmA[1] + (float)vcA[1]);
            a2 = a2*sc + p*((float)vmA[2] + (float)vcA[2]);
            a3 = a3*sc + p*((float)vmA[3] + (float)vcA[3]);

            // rotate pipeline
            cwA = cwB;
            qfA = qfN; kkA = kkN; kcA = kcN; vmA = vmN; vcA = vcN;
            srcB = srcN; cwB = cwN;
        }
    }
    const float inv = (l > 0.f) ? 1.f/l : 0.f;
    a0 *= inv; a1 *= inv; a2 *= inv; a3 *= inv;
    f16x4 o;
    o[0] = (_Float16)(0.5f*a0*(1.f + erff(a0*0.70710678118654752f)));
    o[1] = (_Float16)(0.5f*a1*(1.f + erff(a1*0.70710678118654752f)));
    o[2] = (_Float16)(0.5f*a2*(1.f + erff(a2*0.70710678118654752f)));
    o[3] = (_Float16)(0.5f*a3*(1.f + erff(a3*0.70710678118654752f)));
    *reinterpret_cast<f16x4*>(&agg[(size_t)n*HD + col]) = o;
    if (store_s && (lane & 7) == 0){
        mbuf[(size_t)n*NH + h] = m;
        lbuf[(size_t)n*NH + h] = l;
    }
}

// ---------- alpha output from stored scores (last layer only) ----------
__global__ void k_alpha(const float* __restrict__ s_arr, const int* __restrict__ eid_s,
                        const float* __restrict__ mbuf, const float* __restrict__ lbuf,
                        const int* __restrict__ tgt_srt, float* __restrict__ out_att)
{
    int i = blockIdx.x*256 + threadIdx.x;
    if (i >= NE*NH) return;
    const int j = i >> 3, h = i & 7;
    const int t = tgt_srt[j];
    const float a = __expf(s_arr[i] - mbuf[(size_t)t*NH + h]) / lbuf[(size_t)t*NH + h];
    out_att[(size_t)eid_s[j]*NH + h] = a;
}

extern "C" void kernel_launch(void* const* d_in, const int* in_sizes, int n_in,
                              void* d_out, int out_size, void* d_ws, size_t ws_size,
                              hipStream_t stream)
{
    const float* node_feature = (const float*)d_in[0];
    const int*   node_type    = (const int*)d_in[1];
    const int*   edge_time    = (const int*)d_in[2];
    const int*   edge_index   = (const int*)d_in[3];
    const int*   edge_type    = (const int*)d_in[4];
    const float* adapt_W = (const float*)d_in[5];
    const float* adapt_b = (const float*)d_in[6];
    const float* k_W = (const float*)d_in[7];
    const float* k_b = (const float*)d_in[8];
    const float* q_W = (const float*)d_in[9];
    const float* q_b = (const float*)d_in[10];
    const float* v_W = (const float*)d_in[11];
    const float* v_b = (const float*)d_in[12];
    const float* a_W = (const float*)d_in[13];
    const float* a_b = (const float*)d_in[14];
    const float* rel_pri = (const float*)d_in[15];
    const float* rel_att = (const float*)d_in[16];
    const float* rel_msg = (const float*)d_in[17];
    const float* skip  = (const float*)d_in[18];
    const float* rte_W = (const float*)d_in[19];
    const float* rte_b = (const float*)d_in[20];
    const float* rte_emb = (const float*)d_in[21];

    char* wp = (char*)d_ws;
    auto alloc_f = [&](size_t n)->float*{ float* p=(float*)wp; wp += n*sizeof(float); return p; };
    auto alloc_i = [&](size_t n)->int*  { int*   p=(int*)wp;   wp += n*sizeof(int);   return p; };
    auto alloc_h = [&](size_t n)->_Float16*{ _Float16* p=(_Float16*)wp; wp += n*sizeof(_Float16); return p; };
    _Float16* xh0 = alloc_h((size_t)NN*HD);
    _Float16* xh1 = alloc_h((size_t)NN*HD);
    _Float16* q0h = alloc_h((size_t)NN*HD);
    _Float16* k0h = alloc_h((size_t)NN*HD);
    _Float16* v0h = alloc_h((size_t)NN*HD);
    _Float16* aggh= alloc_h((size_t)NN*HD);
    float* s_arr = alloc_f((size_t)NE*NH);
    float* mbuf  = alloc_f((size_t)NN*NH);
    float* lbuf  = alloc_f((size_t)NN*NH);
    float* rteP  = alloc_f((size_t)MAXL*HD);
    _Float16* Kch0 = alloc_h((size_t)MAXL*NT*HD);
    _Float16* Kch1 = alloc_h((size_t)MAXL*NT*HD);
    _Float16* Vch  = alloc_h((size_t)MAXL*NT*HD);
    _Float16* qfh  = alloc_h((size_t)NN*NR*HD);            // q-fold table (att)
    _Float16* vmh  = alloc_h((size_t)NN*NR*HD);            // msg node table
    _Float16* kcaM0 = alloc_h((size_t)MAXL*NT*NR*HD);
    _Float16* kcaM1 = alloc_h((size_t)MAXL*NT*NR*HD);
    _Float16* wF   = alloc_h((size_t)36*65536);
    _Float16* relF = alloc_h((size_t)256*1024);
    int* nbucket = alloc_i(NN);
    int* nhist   = alloc_i(HBLK*NT);
    int* nbase   = alloc_i(HBLK*NT);
    int* noff    = alloc_i(8);
    int* tlist   = alloc_i(TMAX);
    int* tcount  = alloc_i(8);
    int* cnt     = alloc_i(NN);
    int* bsum    = alloc_i(SCB);
    int* bbase   = alloc_i(SCB);
    int* binCur  = alloc_i(NN);
    int* tgt_off = alloc_i(NN+1);
    int* src_s   = alloc_i(NE);
    int* combo_s = alloc_i(NE);
    int* eid_s   = alloc_i(NE);
    int* tgt_srt = alloc_i(NE);

    const _Float16* adaptF = wF;
    const _Float16* qF = wF + (size_t)4*65536;
    const _Float16* kF = wF + (size_t)12*65536;
    const _Float16* vF = wF + (size_t)20*65536;
    const _Float16* aF = wF + (size_t)28*65536;
    const _Float16* relAF = relF;                 // transposed-packed (q-side fold)
    const _Float16* relMF = relF + (size_t)128*1024;

    float* out_att = (float*)d_out;
    float* out_x   = (float*)d_out + (size_t)NE*NH;

    const dim3 gFoldC(FOLDC, NR);
    const dim3 gQKV(TMAX, 3);
    const int gFoldX = 1024;
    const int gE256 = (NE + 255)/256;
    const int gEH = (NE*NH + 255)/256;
    const int gN256 = (NN + 255)/256;
    const int gEg = (NN + 3)/4;

    // weight pre-pack
    k_w2f16_big<<<dim3(64,36),256,0,stream>>>(adapt_W, q_W, k_W, v_W, a_W, wF);
    k_w2f16_rel<<<dim3(1,256),256,0,stream>>>(rel_att, rel_msg, relF);

    // node buckets + tile list
    k_nhist<<<HBLK,256,0,stream>>>(node_type, nhist);
    k_nscan<<<1,64,0,stream>>>(nhist, noff, nbase, tlist, tcount);
    k_nscatter<<<HBLK,256,0,stream>>>(node_type, nbase, nbucket);

    // edge CSR sorted by tgt
    k_zero_bins<<<SCB,256,0,stream>>>(cnt);
    k_csr_hist<<<gE256,256,0,stream>>>(edge_index, cnt);
    k_scan1<<<SCB,256,0,stream>>>(cnt, tgt_off, bsum);
    k_scan2<<<1,128,0,stream>>>(bsum, bbase, tgt_off);
    k_scan3<<<SCB,256,0,stream>>>(tgt_off, bbase, binCur);
    k_csr_scatter<<<gE256,256,0,stream>>>(edge_index, edge_type, edge_time, node_type,
                                          binCur, src_s, combo_s, eid_s);
    k_tgtmap<<<gN256,256,0,stream>>>(tgt_off, tgt_srt);

    // preamble: per-layer combo K tables (unfolded) + msg combo folds
    {
        k_row_gemm<<<MAXL,256,0,stream>>>(rte_emb, rte_W, rte_b, rteP);
        k_row_gemm2<<<dim3(MAXL,NT,2),256,0,stream>>>(rteP, k_W, v_W, Kch0, Vch);
        k_fold2<<<gFoldC,256,0,stream>>>(Vch, relMF, kcaM0, MAXL*NT, FOLDC);
        k_row_gemm<<<MAXL,256,0,stream>>>(rte_emb, rte_W + (size_t)HD*HD, rte_b + HD, rteP);
        k_row_gemm2<<<dim3(MAXL,NT,2),256,0,stream>>>(rteP, k_W + (size_t)NT*HD*HD,
                                                      v_W + (size_t)NT*HD*HD, Kch1, Vch);
        k_fold2<<<gFoldC,256,0,stream>>>(Vch, relMF + (size_t)NR*NH*1024, kcaM1, MAXL*NT, FOLDC);
    }

    // adapt -> xh0 (f16), then split QKV(l=0)
    k_x<<<TMAX,256,0,stream>>>(node_feature, nullptr, adaptF, adapt_b, xh0,
                               nbucket, noff, tlist, tcount, 1, 1, nullptr, nullptr);
    k_qkv<<<gQKV,256,0,stream>>>(xh0, qF, q_b, q0h, kF, k_b, k0h, vF, v_b, v0h,
                                 nbucket, noff, tlist, tcount);

    for (int l = 0; l < NL; l++){
        const _Float16* rAF = relAF + (size_t)l*NR*NH*1024;
        const _Float16* rMF = relMF + (size_t)l*NR*NH*1024;
        const _Float16* KchL = (l == 0) ? Kch0 : Kch1;
        const _Float16* kcaM = (l == 0) ? kcaM0 : kcaM1;
        const int store_s = (l == NL-1) ? 1 : 0;
        // node folds: q-fold (att, transposed rel) + v-fold (msg)
        k_fold2x<<<gFoldX,256,0,stream>>>(q0h, rAF, qfh, v0h, rMF, vmh);
        // fused score + online softmax + aggregate + gelu
        k_edge<<<gEg,256,0,stream>>>(qfh, k0h, KchL, vmh, kcaM,
                                     rel_pri + (size_t)l*NR*NH,
                                     tgt_off, src_s, combo_s, aggh,
                                     s_arr, mbuf, lbuf, store_s);
        if (store_s)
            k_alpha<<<gEH,256,0,stream>>>(s_arr, eid_s, mbuf, lbuf, tgt_srt, out_att);
        // aW(l); next-layer x + QKV if not last
        if (l == 0){
            k_x<<<TMAX,256,0,stream>>>(nullptr, aggh, aF, a_b, xh1,
                                       nbucket, noff, tlist, tcount, 2, 1, skip, xh0);
            k_qkv<<<gQKV,256,0,stream>>>(xh1, qF + (size_t)NT*HD*HD, q_b + (size_t)NT*HD, q0h,
                                         kF + (size_t)NT*HD*HD, k_b + (size_t)NT*HD, k0h,
                                         vF + (size_t)NT*HD*HD, v_b + (size_t)NT*HD, v0h,
                                         nbucket, noff, tlist, tcount);
        } else {
            k_x<<<TMAX,256,0,stream>>>(nullptr, aggh, aF + (size_t)NT*HD*HD, a_b + (size_t)NT*HD,
                                       out_x, nbucket, noff, tlist, tcount, 2, 0, skip + NT, xh1);
        }
    }
}